// Round 5
// baseline (364.965 us; speedup 1.0000x reference)
//
#include <hip/hip_runtime.h>

#define BB 8
#define TT 1024
#define DD 512
#define DD2 1024
#define HH 8
#define HDIM 64
#define TP (TT + 2)

typedef short short8 __attribute__((ext_vector_type(8)));
typedef float floatx4 __attribute__((ext_vector_type(4)));

typedef const __attribute__((address_space(1))) unsigned int* gas_ptr;
typedef __attribute__((address_space(3))) unsigned int* las_ptr;

__device__ __forceinline__ unsigned short f2bf(float f) {
    union { float f; unsigned u; } v; v.f = f;
    unsigned r = v.u + 0x7fffu + ((v.u >> 16) & 1u);
    return (unsigned short)(r >> 16);
}

// async global->LDS, 16B per lane, LDS dst = wave-uniform base + lane*16
__device__ __forceinline__ void gl2lds16(const void* g, void* l) {
    __builtin_amdgcn_global_load_lds((gas_ptr)g, (las_ptr)l, 16, 0, 0);
}

// ---------------- prep kernels ----------------
__global__ void k_convert_x(const float* __restrict__ x, unsigned short* __restrict__ xp) {
    int idx = blockIdx.x * 256 + threadIdx.x;
    const int total = BB * TP * DD;
    if (idx >= total) return;
    int c = idx % DD;
    int rt = idx / DD;
    int row = rt % TP;
    int b = rt / TP;
    float v = 0.f;
    if (row >= 1 && row <= TT) v = x[(b * TT + row - 1) * DD + c];
    xp[idx] = f2bf(v);
}

__global__ void k_convert_wqkv(const float* __restrict__ w0, const float* __restrict__ w1,
                               const float* __restrict__ w2, unsigned short* __restrict__ out) {
    int idx = blockIdx.x * 256 + threadIdx.x;
    const int total = 3 * 3 * DD * DD;
    if (idx >= total) return;
    int ci = idx % DD;
    int t1 = idx / DD;
    int co = t1 % DD;
    int t2 = t1 / DD;
    int k = t2 % 3;
    int p = t2 / 3;
    const float* w = (p == 0) ? w0 : ((p == 1) ? w1 : w2);
    out[idx] = f2bf(w[(co * DD + ci) * 3 + k]);
}

__global__ void k_convert_w2(const float* __restrict__ w, unsigned short* __restrict__ out) {
    int idx = blockIdx.x * 256 + threadIdx.x;
    const int total = 3 * DD * DD2;
    if (idx >= total) return;
    int ci = idx % DD2;
    int t1 = idx / DD2;
    int co = t1 % DD;
    int k = t1 / DD;
    out[idx] = f2bf(w[(co * DD2 + ci) * 3 + k]);
}

__global__ void k_zero_aux(unsigned short* __restrict__ vp, float* __restrict__ gbuf) {
    int idx = blockIdx.x * 256 + threadIdx.x;
    if (idx < BB * 2 * 2 * DD) {
        int c = idx % (2 * DD);
        int t1 = idx / (2 * DD);
        int row = (t1 & 1) ? (TT + 1) : 0;
        int b = t1 >> 1;
        vp[(b * TP + row) * (2 * DD) + c] = 0;
    }
    if (idx < 64 * HDIM * HDIM) gbuf[idx] = 0.f;
}

// ---------------- QKV conv: m97-style 128x128 tile, BK=32, LDS staged ----------------
// grid (T/128=8, 512/128=4, B*3=24), 256 thr = 4 waves (2x2), wave tile 64x64
__global__ __launch_bounds__(256) void k_qkv_conv(
    const unsigned short* __restrict__ xp, const unsigned short* __restrict__ wqkv,
    const float* __restrict__ b11, const float* __restrict__ b12, const float* __restrict__ b13,
    unsigned short* __restrict__ q, unsigned short* __restrict__ qt,
    unsigned short* __restrict__ kbuf, unsigned short* __restrict__ kt,
    unsigned short* __restrict__ v, unsigned short* __restrict__ vt) {
    __shared__ short As[144 * 32];      // rows tb..tb+143 (halo; only 0..129 used)
    __shared__ short Ws[3 * 128 * 32];  // [k][co 128][ci 32]
    int wave = threadIdx.x >> 6, lane = threadIdx.x & 63;
    int l15 = lane & 15, quad = lane >> 4;
    int wm = wave >> 1, wn = wave & 1;
    int tb = blockIdx.x * 128;
    int cb = blockIdx.y * 128;
    int proj = blockIdx.z % 3, b = blockIdx.z / 3;
    const short* A = (const short*)xp + b * TP * DD;
    const short* W = (const short*)wqkv + proj * 3 * DD * DD;
    int srow = lane >> 2;       // staging: lane -> row 0..15
    int scol = (lane & 3) * 8;  // staging: lane -> col (8 bf16 = 16B)

    floatx4 acc[4][4];
#pragma unroll
    for (int mi = 0; mi < 4; ++mi)
#pragma unroll
        for (int ni = 0; ni < 4; ++ni) acc[mi][ni] = (floatx4){0.f, 0.f, 0.f, 0.f};

    for (int ci = 0; ci < DD; ci += 32) {
        if (ci) __syncthreads();
        for (int j = wave; j < 33; j += 4) {
            if (j < 9) {
                gl2lds16(A + (tb + j * 16 + srow) * DD + ci + scol, &As[j * 512]);
            } else {
                int jj = j - 9;
                int k = jj >> 3;
                gl2lds16(W + k * DD * DD + (cb + (jj & 7) * 16 + srow) * DD + ci + scol,
                         &Ws[jj * 512]);
            }
        }
        __syncthreads();
#pragma unroll
        for (int k = 0; k < 3; ++k) {
            short8 af[4], bf[4];
#pragma unroll
            for (int mi = 0; mi < 4; ++mi)
                af[mi] = *(const short8*)&As[(wm * 64 + mi * 16 + l15 + k) * 32 + quad * 8];
#pragma unroll
            for (int ni = 0; ni < 4; ++ni)
                bf[ni] = *(const short8*)&Ws[(k * 128 + wn * 64 + ni * 16 + l15) * 32 + quad * 8];
#pragma unroll
            for (int mi = 0; mi < 4; ++mi)
#pragma unroll
                for (int ni = 0; ni < 4; ++ni)
                    acc[mi][ni] = __builtin_amdgcn_mfma_f32_16x16x32_bf16(af[mi], bf[ni], acc[mi][ni], 0, 0, 0);
        }
    }

    const float* bias = (proj == 0) ? b11 : ((proj == 1) ? b12 : b13);
    unsigned short* o1 = (proj == 0) ? q : ((proj == 1) ? kbuf : v);
    unsigned short* o2 = (proj == 0) ? qt : ((proj == 1) ? kt : vt);
#pragma unroll
    for (int ni = 0; ni < 4; ++ni) {
        int co = cb + wn * 64 + ni * 16 + l15;
        float bv = bias[co];
        int h = co >> 6, hd = co & 63;
#pragma unroll
        for (int mi = 0; mi < 4; ++mi) {
            int tbase = tb + wm * 64 + mi * 16 + quad * 4;
            ushort4 pk;
#pragma unroll
            for (int r = 0; r < 4; ++r) {
                float val = fmaxf(acc[mi][ni][r] + bv, 0.f);
                unsigned short bb = f2bf(val);
                o1[((b * HH + h) * TT + tbase + r) * HDIM + hd] = bb;
                ((unsigned short*)&pk)[r] = bb;
            }
            *(ushort4*)&o2[((b * HH + h) * HDIM + hd) * TT + tbase] = pk;
        }
    }
}

// ---------------- time attention: all-register flash (no LDS, no barriers) ----------------
// grid (T/64=16, B*H=64), block 256; each wave owns 16 Q rows (q = l15).
// S^T = K.Q^T with PERMUTED K rows per MFMA so each lane lands exactly on the
// P^T B-fragment layout (s = quad*8+j). No max-subtraction (post-ReLU scores >= 0,
// bounded). PV computes O^T = Vt . P^T; output C-layout packs to b64 global stores.
__global__ __launch_bounds__(256) void k_time_attn(
    const unsigned short* __restrict__ q, const unsigned short* __restrict__ kbuf,
    const unsigned short* __restrict__ vt, unsigned short* __restrict__ vp) {
    int wave = threadIdx.x >> 6, lane = threadIdx.x & 63;
    int l15 = lane & 15, quad = lane >> 4;
    int bh = blockIdx.y;
    int b = bh >> 3, h = bh & 7;
    int qr = blockIdx.x * 64 + wave * 16;
    const short* Q = (const short*)q + bh * TT * HDIM;
    const short* K = (const short*)kbuf + bh * TT * HDIM;
    const short* Vt = (const short*)vt + bh * HDIM * TT;

    // Q rows as B-operand of S^T = K.Q^T (n = q = l15)
    short8 bq[2];
#pragma unroll
    for (int kf = 0; kf < 2; ++kf)
        bq[kf] = *(const short8*)(Q + (qr + l15) * HDIM + kf * 32 + quad * 8);

    // permuted K row base: MFMA jr row m=l15 takes K row (m>>2)*8 + (m&3) + (jr&1)*4 + (jr>>1)*32
    int krow_base = (l15 >> 2) * 8 + (l15 & 3);

    floatx4 o[4];  // O^T accum: d = df*16 + quad*4 + r, q = l15
#pragma unroll
    for (int df = 0; df < 4; ++df) o[df] = (floatx4){0.f, 0.f, 0.f, 0.f};
    float lacc = 0.f;  // sum of this lane's P values (q = l15)

    for (int s = 0; s < TT; s += 64) {
        floatx4 c[4];
#pragma unroll
        for (int jr = 0; jr < 4; ++jr) c[jr] = (floatx4){0.f, 0.f, 0.f, 0.f};
#pragma unroll
        for (int jr = 0; jr < 4; ++jr) {
            int krow = s + krow_base + (jr & 1) * 4 + (jr >> 1) * 32;
#pragma unroll
            for (int kf = 0; kf < 2; ++kf) {
                short8 ak = *(const short8*)(K + krow * HDIM + kf * 32 + quad * 8);
                c[jr] = __builtin_amdgcn_mfma_f32_16x16x32_bf16(ak, bq[kf], c[jr], 0, 0, 0);
            }
        }
        // After permutation, lane (l15,quad) holds s-offsets {quad*8..+7} (c0,c1) and
        // {32+quad*8..+7} (c2,c3): exactly the PV B-fragment. exp + pack in-register.
        short8 pb[2];
#pragma unroll
        for (int kf = 0; kf < 2; ++kf) {
            union { short8 s; unsigned u[4]; } pk;
#pragma unroll
            for (int half = 0; half < 2; ++half) {
                floatx4 cc = c[2 * kf + half];
                float p0 = __expf(cc[0] * 0.125f);
                float p1 = __expf(cc[1] * 0.125f);
                float p2 = __expf(cc[2] * 0.125f);
                float p3 = __expf(cc[3] * 0.125f);
                lacc += (p0 + p1) + (p2 + p3);
                pk.u[half * 2] =
                    __builtin_amdgcn_perm(__float_as_uint(p1), __float_as_uint(p0), 0x07060302u);
                pk.u[half * 2 + 1] =
                    __builtin_amdgcn_perm(__float_as_uint(p3), __float_as_uint(p2), 0x07060302u);
            }
            pb[kf] = pk.s;
        }
        // O^T += Vt . P^T  (A = Vt rows, B = pb)
#pragma unroll
        for (int df = 0; df < 4; ++df) {
#pragma unroll
            for (int kf = 0; kf < 2; ++kf) {
                short8 av = *(const short8*)(Vt + (df * 16 + l15) * TT + s + kf * 32 + quad * 8);
                o[df] = __builtin_amdgcn_mfma_f32_16x16x32_bf16(av, pb[kf], o[df], 0, 0, 0);
            }
        }
    }

    // total l for q=l15: sum across the 4 quads holding this q
    lacc += __shfl_xor(lacc, 16);
    lacc += __shfl_xor(lacc, 32);
    float linv = 1.f / lacc;

    // store O[t=qr+l15][h*64 + df*16 + quad*4 + r] as packed b64
    unsigned short* vrow = vp + (size_t)(b * TP + 1 + qr + l15) * (2 * DD) + h * 64;
#pragma unroll
    for (int df = 0; df < 4; ++df) {
        ushort4 pk;
#pragma unroll
        for (int r = 0; r < 4; ++r) ((unsigned short*)&pk)[r] = f2bf(o[df][r] * linv);
        *(ushort4*)&vrow[df * 16 + quad * 4] = pk;
    }
}

// ---------------- channel attention: Gram partials (4-way T split) ----------------
// grid (4, B*H=64), block 256; wave w owns c-rows [16w,16w+16)
__global__ __launch_bounds__(256) void k_chan_gram(
    const unsigned short* __restrict__ qt, const unsigned short* __restrict__ kt,
    float* __restrict__ gbuf) {
    int wave = threadIdx.x >> 6, lane = threadIdx.x & 63;
    int l15 = lane & 15, quad = lane >> 4;
    int tc = blockIdx.x, bh = blockIdx.y;
    const short* Qt = (const short*)qt + bh * HDIM * TT;
    const short* Kt = (const short*)kt + bh * HDIM * TT;

    floatx4 g[4];
#pragma unroll
    for (int nt = 0; nt < 4; ++nt) g[nt] = (floatx4){0.f, 0.f, 0.f, 0.f};

    int t0b = tc * 256;
    for (int t0 = 0; t0 < 256; t0 += 32) {
        short8 aq = *(const short8*)(Qt + (wave * 16 + l15) * TT + t0b + t0 + quad * 8);
#pragma unroll
        for (int nt = 0; nt < 4; ++nt) {
            short8 bk = *(const short8*)(Kt + (nt * 16 + l15) * TT + t0b + t0 + quad * 8);
            g[nt] = __builtin_amdgcn_mfma_f32_16x16x32_bf16(aq, bk, g[nt], 0, 0, 0);
        }
    }
    float* gb = gbuf + bh * HDIM * HDIM;
#pragma unroll
    for (int nt = 0; nt < 4; ++nt) {
#pragma unroll
        for (int r = 0; r < 4; ++r) {
            int row = wave * 16 + quad * 4 + r;
            atomicAdd(&gb[row * HDIM + nt * 16 + l15], g[nt][r]);
        }
    }
}

// ---------------- channel attention: softmax + A.V (4-way T split) ----------------
// grid (4, B*H=64), block 256
__global__ __launch_bounds__(256) void k_chan_av(
    const float* __restrict__ gbuf, const unsigned short* __restrict__ v,
    unsigned short* __restrict__ vp) {
    __shared__ short lds_a[64 * 64];
    int wave = threadIdx.x >> 6, lane = threadIdx.x & 63;
    int l15 = lane & 15, quad = lane >> 4;
    int tc = blockIdx.x, bh = blockIdx.y;
    int b = bh >> 3, h = bh & 7;
    const float sc = 0.03125f;  // 1/sqrt(1024)

    if (threadIdx.x < 64) {
        const float* gb = gbuf + bh * HDIM * HDIM + threadIdx.x * HDIM;
        float mx = -3.0e38f;
        for (int j = 0; j < 64; ++j) mx = fmaxf(mx, gb[j] * sc);
        float sum = 0.f;
        for (int j = 0; j < 64; ++j) sum += __expf(gb[j] * sc - mx);
        float inv = 1.f / sum;
        for (int j = 0; j < 64; ++j)
            lds_a[threadIdx.x * 64 + j] = (short)f2bf(__expf(gb[j] * sc - mx) * inv);
    }
    __syncthreads();

    const short* V = (const short*)v + bh * TT * HDIM;
    short8 pa[2];
#pragma unroll
    for (int kf = 0; kf < 2; ++kf)
        pa[kf] = *(const short8*)&lds_a[(wave * 16 + l15) * 64 + kf * 32 + quad * 8];

    for (int tt = 0; tt < 16; ++tt) {
        int ttile = tc * 16 + tt;
        floatx4 c = (floatx4){0.f, 0.f, 0.f, 0.f};
#pragma unroll
        for (int kf = 0; kf < 2; ++kf) {
            short8 bv = *(const short8*)(V + (ttile * 16 + l15) * HDIM + kf * 32 + quad * 8);
            c = __builtin_amdgcn_mfma_f32_16x16x32_bf16(pa[kf], bv, c, 0, 0, 0);
        }
        int t = ttile * 16 + l15;
#pragma unroll
        for (int r = 0; r < 4; ++r) {
            int crow = wave * 16 + quad * 4 + r;
            int tout = crow * 16 + (t >> 6);
            int col = 512 + ((t & 63) << 3) + h;
            vp[(b * TP + 1 + tout) * (2 * DD) + col] = f2bf(c[r]);
        }
    }
}

// ---------------- output conv: 128x128 tile, BK=32, LDS staged ----------------
// grid (T/128=8, 512/128=4, B=8)
__global__ __launch_bounds__(256) void k_out_conv(
    const unsigned short* __restrict__ vp, const unsigned short* __restrict__ w2k,
    const float* __restrict__ b2, float* __restrict__ out) {
    __shared__ short As[144 * 32];
    __shared__ short Ws[3 * 128 * 32];
    int wave = threadIdx.x >> 6, lane = threadIdx.x & 63;
    int l15 = lane & 15, quad = lane >> 4;
    int wm = wave >> 1, wn = wave & 1;
    int tb = blockIdx.x * 128;
    int cb = blockIdx.y * 128;
    int b = blockIdx.z;
    const short* A = (const short*)vp + b * TP * DD2;
    const short* W = (const short*)w2k;
    int srow = lane >> 2;
    int scol = (lane & 3) * 8;

    floatx4 acc[4][4];
#pragma unroll
    for (int mi = 0; mi < 4; ++mi)
#pragma unroll
        for (int ni = 0; ni < 4; ++ni) acc[mi][ni] = (floatx4){0.f, 0.f, 0.f, 0.f};

    for (int ci = 0; ci < DD2; ci += 32) {
        if (ci) __syncthreads();
        for (int j = wave; j < 33; j += 4) {
            if (j < 9) {
                gl2lds16(A + (tb + j * 16 + srow) * DD2 + ci + scol, &As[j * 512]);
            } else {
                int jj = j - 9;
                int k = jj >> 3;
                gl2lds16(W + (k * DD + cb + (jj & 7) * 16 + srow) * DD2 + ci + scol,
                         &Ws[jj * 512]);
            }
        }
        __syncthreads();
#pragma unroll
        for (int k = 0; k < 3; ++k) {
            short8 af[4], bf[4];
#pragma unroll
            for (int mi = 0; mi < 4; ++mi)
                af[mi] = *(const short8*)&As[(wm * 64 + mi * 16 + l15 + k) * 32 + quad * 8];
#pragma unroll
            for (int ni = 0; ni < 4; ++ni)
                bf[ni] = *(const short8*)&Ws[(k * 128 + wn * 64 + ni * 16 + l15) * 32 + quad * 8];
#pragma unroll
            for (int mi = 0; mi < 4; ++mi)
#pragma unroll
                for (int ni = 0; ni < 4; ++ni)
                    acc[mi][ni] = __builtin_amdgcn_mfma_f32_16x16x32_bf16(af[mi], bf[ni], acc[mi][ni], 0, 0, 0);
        }
    }

#pragma unroll
    for (int ni = 0; ni < 4; ++ni) {
        int co = cb + wn * 64 + ni * 16 + l15;
        float bv = b2[co];
#pragma unroll
        for (int mi = 0; mi < 4; ++mi) {
#pragma unroll
            for (int r = 0; r < 4; ++r) {
                int t = tb + wm * 64 + mi * 16 + quad * 4 + r;
                out[(b * TT + t) * DD + co] = fmaxf(acc[mi][ni][r] + bv, 0.f);
            }
        }
    }
}

extern "C" void kernel_launch(void* const* d_in, const int* in_sizes, int n_in,
                              void* d_out, int out_size, void* d_ws, size_t ws_size,
                              hipStream_t stream) {
    const float* x = (const float*)d_in[0];
    const float* w11 = (const float*)d_in[1];
    const float* b11 = (const float*)d_in[2];
    const float* w12 = (const float*)d_in[3];
    const float* b12 = (const float*)d_in[4];
    const float* w13 = (const float*)d_in[5];
    const float* b13 = (const float*)d_in[6];
    const float* w2 = (const float*)d_in[7];
    const float* b2 = (const float*)d_in[8];
    float* out = (float*)d_out;

    char* ws = (char*)d_ws;
    size_t off = 0;
    auto alloc = [&](size_t bytes) {
        void* p = ws + off;
        off += (bytes + 255) & ~(size_t)255;
        return p;
    };
    unsigned short* xp = (unsigned short*)alloc((size_t)BB * TP * DD * 2);
    unsigned short* wqkv = (unsigned short*)alloc((size_t)9 * DD * DD * 2);
    unsigned short* w2k = (unsigned short*)alloc((size_t)3 * DD * DD2 * 2);
    unsigned short* q = (unsigned short*)alloc((size_t)BB * HH * TT * HDIM * 2);
    unsigned short* qt = (unsigned short*)alloc((size_t)BB * HH * TT * HDIM * 2);
    unsigned short* k = (unsigned short*)alloc((size_t)BB * HH * TT * HDIM * 2);
    unsigned short* kt = (unsigned short*)alloc((size_t)BB * HH * TT * HDIM * 2);
    unsigned short* v = (unsigned short*)alloc((size_t)BB * HH * TT * HDIM * 2);
    unsigned short* vt = (unsigned short*)alloc((size_t)BB * HH * TT * HDIM * 2);
    float* gbuf = (float*)alloc((size_t)64 * HDIM * HDIM * 4);
    unsigned short* vp = (unsigned short*)alloc((size_t)BB * TP * 2 * DD * 2);
    (void)alloc(65536);  // guard: halo staging reads up to 14 rows past vp end

    k_convert_x<<<(BB * TP * DD + 255) / 256, 256, 0, stream>>>(x, xp);
    k_convert_wqkv<<<(3 * 3 * DD * DD + 255) / 256, 256, 0, stream>>>(w11, w12, w13, wqkv);
    k_convert_w2<<<(3 * DD * DD2 + 255) / 256, 256, 0, stream>>>(w2, w2k);
    k_zero_aux<<<(64 * HDIM * HDIM + 255) / 256, 256, 0, stream>>>(vp, gbuf);
    k_qkv_conv<<<dim3(TT / 128, DD / 128, BB * 3), 256, 0, stream>>>(xp, wqkv, b11, b12, b13,
                                                                     q, qt, k, kt, v, vt);
    k_time_attn<<<dim3(TT / 64, BB * HH), 256, 0, stream>>>(q, k, vt, vp);
    k_chan_gram<<<dim3(4, BB * HH), 256, 0, stream>>>(qt, kt, gbuf);
    k_chan_av<<<dim3(4, BB * HH), 256, 0, stream>>>(gbuf, v, vp);
    k_out_conv<<<dim3(TT / 128, DD / 128, BB), 256, 0, stream>>>(vp, w2k, b2, out);
}

// Round 6
// 288.269 us; speedup vs baseline: 1.2661x; 1.2661x over previous
//
#include <hip/hip_runtime.h>

#define BB 8
#define TT 1024
#define DD 512
#define DD2 1024
#define HH 8
#define HDIM 64
#define TP (TT + 2)

typedef short short8 __attribute__((ext_vector_type(8)));
typedef float floatx4 __attribute__((ext_vector_type(4)));

typedef const __attribute__((address_space(1))) unsigned int* gas_ptr;
typedef __attribute__((address_space(3))) unsigned int* las_ptr;

__device__ __forceinline__ unsigned short f2bf(float f) {
    union { float f; unsigned u; } v; v.f = f;
    unsigned r = v.u + 0x7fffu + ((v.u >> 16) & 1u);
    return (unsigned short)(r >> 16);
}

// async global->LDS, 16B per lane, LDS dst = wave-uniform base + lane*16
__device__ __forceinline__ void gl2lds16(const void* g, void* l) {
    __builtin_amdgcn_global_load_lds((gas_ptr)g, (las_ptr)l, 16, 0, 0);
}

// ---------------- prep kernels ----------------
__global__ void k_convert_x(const float* __restrict__ x, unsigned short* __restrict__ xp) {
    int idx = blockIdx.x * 256 + threadIdx.x;
    const int total = BB * TP * DD;
    if (idx >= total) return;
    int c = idx % DD;
    int rt = idx / DD;
    int row = rt % TP;
    int b = rt / TP;
    float v = 0.f;
    if (row >= 1 && row <= TT) v = x[(b * TT + row - 1) * DD + c];
    xp[idx] = f2bf(v);
}

__global__ void k_convert_wqkv(const float* __restrict__ w0, const float* __restrict__ w1,
                               const float* __restrict__ w2, unsigned short* __restrict__ out) {
    int idx = blockIdx.x * 256 + threadIdx.x;
    const int total = 3 * 3 * DD * DD;
    if (idx >= total) return;
    int ci = idx % DD;
    int t1 = idx / DD;
    int co = t1 % DD;
    int t2 = t1 / DD;
    int k = t2 % 3;
    int p = t2 / 3;
    const float* w = (p == 0) ? w0 : ((p == 1) ? w1 : w2);
    out[idx] = f2bf(w[(co * DD + ci) * 3 + k]);
}

__global__ void k_convert_w2(const float* __restrict__ w, unsigned short* __restrict__ out) {
    int idx = blockIdx.x * 256 + threadIdx.x;
    const int total = 3 * DD * DD2;
    if (idx >= total) return;
    int ci = idx % DD2;
    int t1 = idx / DD2;
    int co = t1 % DD;
    int k = t1 / DD;
    out[idx] = f2bf(w[(co * DD2 + ci) * 3 + k]);
}

__global__ void k_zero_aux(unsigned short* __restrict__ vp, float* __restrict__ gbuf) {
    int idx = blockIdx.x * 256 + threadIdx.x;
    if (idx < BB * 2 * 2 * DD) {
        int c = idx % (2 * DD);
        int t1 = idx / (2 * DD);
        int row = (t1 & 1) ? (TT + 1) : 0;
        int b = t1 >> 1;
        vp[(b * TP + row) * (2 * DD) + c] = 0;
    }
    if (idx < 64 * HDIM * HDIM) gbuf[idx] = 0.f;
}

// ---------------- QKV conv: m97-style 128x128 tile, BK=32, LDS staged ----------------
// grid (T/128=8, 512/128=4, B*3=24), 256 thr = 4 waves (2x2), wave tile 64x64
// K and V^T are stored in MFMA-fragment-major layout (lane-linear 16B chunks) so the
// attention kernel's hot-loop loads are fully coalesced (4 transactions/instr).
__global__ __launch_bounds__(256) void k_qkv_conv(
    const unsigned short* __restrict__ xp, const unsigned short* __restrict__ wqkv,
    const float* __restrict__ b11, const float* __restrict__ b12, const float* __restrict__ b13,
    unsigned short* __restrict__ q, unsigned short* __restrict__ qt,
    unsigned short* __restrict__ kfrag, unsigned short* __restrict__ kt,
    unsigned short* __restrict__ v, unsigned short* __restrict__ vtfrag) {
    __shared__ short As[144 * 32];      // rows tb..tb+143 (halo; only 0..129 used)
    __shared__ short Ws[3 * 128 * 32];  // [k][co 128][ci 32]
    int wave = threadIdx.x >> 6, lane = threadIdx.x & 63;
    int l15 = lane & 15, quad = lane >> 4;
    int wm = wave >> 1, wn = wave & 1;
    int tb = blockIdx.x * 128;
    int cb = blockIdx.y * 128;
    int proj = blockIdx.z % 3, b = blockIdx.z / 3;
    const short* A = (const short*)xp + b * TP * DD;
    const short* W = (const short*)wqkv + proj * 3 * DD * DD;
    int srow = lane >> 2;       // staging: lane -> row 0..15
    int scol = (lane & 3) * 8;  // staging: lane -> col (8 bf16 = 16B)

    floatx4 acc[4][4];
#pragma unroll
    for (int mi = 0; mi < 4; ++mi)
#pragma unroll
        for (int ni = 0; ni < 4; ++ni) acc[mi][ni] = (floatx4){0.f, 0.f, 0.f, 0.f};

    for (int ci = 0; ci < DD; ci += 32) {
        if (ci) __syncthreads();
        for (int j = wave; j < 33; j += 4) {
            if (j < 9) {
                gl2lds16(A + (tb + j * 16 + srow) * DD + ci + scol, &As[j * 512]);
            } else {
                int jj = j - 9;
                int k = jj >> 3;
                gl2lds16(W + k * DD * DD + (cb + (jj & 7) * 16 + srow) * DD + ci + scol,
                         &Ws[jj * 512]);
            }
        }
        __syncthreads();
#pragma unroll
        for (int k = 0; k < 3; ++k) {
            short8 af[4], bf[4];
#pragma unroll
            for (int mi = 0; mi < 4; ++mi)
                af[mi] = *(const short8*)&As[(wm * 64 + mi * 16 + l15 + k) * 32 + quad * 8];
#pragma unroll
            for (int ni = 0; ni < 4; ++ni)
                bf[ni] = *(const short8*)&Ws[(k * 128 + wn * 64 + ni * 16 + l15) * 32 + quad * 8];
#pragma unroll
            for (int mi = 0; mi < 4; ++mi)
#pragma unroll
                for (int ni = 0; ni < 4; ++ni)
                    acc[mi][ni] = __builtin_amdgcn_mfma_f32_16x16x32_bf16(af[mi], bf[ni], acc[mi][ni], 0, 0, 0);
        }
    }

    const float* bias = (proj == 0) ? b11 : ((proj == 1) ? b12 : b13);
#pragma unroll
    for (int ni = 0; ni < 4; ++ni) {
        int co = cb + wn * 64 + ni * 16 + l15;
        float bv = bias[co];
        int h = co >> 6, hd = co & 63;
        int bh = b * HH + h;
#pragma unroll
        for (int mi = 0; mi < 4; ++mi) {
            int tbase = tb + wm * 64 + mi * 16 + quad * 4;
            unsigned short bb[4];
            ushort4 pk;
#pragma unroll
            for (int r = 0; r < 4; ++r) {
                float val = fmaxf(acc[mi][ni][r] + bv, 0.f);
                bb[r] = f2bf(val);
                ((unsigned short*)&pk)[r] = bb[r];
            }
            if (proj == 0) {
#pragma unroll
                for (int r = 0; r < 4; ++r)
                    q[((size_t)bh * TT + tbase + r) * HDIM + hd] = bb[r];
                *(ushort4*)&qt[((size_t)bh * HDIM + hd) * TT + tbase] = pk;
            } else if (proj == 1) {
                *(ushort4*)&kt[((size_t)bh * HDIM + hd) * TT + tbase] = pk;
                // K-frag layout: [bh][sblk][jr][kf][quad_a*16+l15a][8]
                int sblk = tbase >> 6;
                int jr = (quad & 1) + 2 * (mi >> 1);
                int l15a_base = 4 * (quad >> 1) + 8 * (mi & 1);  // + r
                int kf = hd >> 5, quad_a = (hd >> 3) & 3, elem = hd & 7;
                size_t base = ((((size_t)bh * 16 + sblk) * 4 + jr) * 2 + kf) * 512 +
                              quad_a * 128 + elem;
#pragma unroll
                for (int r = 0; r < 4; ++r)
                    kfrag[base + (l15a_base + r) * 8] = bb[r];
            } else {
#pragma unroll
                for (int r = 0; r < 4; ++r)
                    v[((size_t)bh * TT + tbase + r) * HDIM + hd] = bb[r];
                // Vt-frag layout: [bh][sblk][df][kf][quad_a*16+l15a][8]
                int sblk = tbase >> 6;
                int df = hd >> 4, l15a = hd & 15;
                int kf = mi >> 1;
                int quad_a = 2 * (mi & 1) + (quad >> 1);
                int elem = (quad & 1) * 4;
                size_t base = ((((size_t)bh * 16 + sblk) * 4 + df) * 2 + kf) * 512 +
                              (quad_a * 16 + l15a) * 8 + elem;
                *(ushort4*)&vtfrag[base] = pk;
            }
        }
    }
}

// ---------------- time attention: all-register flash, lane-linear frag loads ----------
// grid (T/64=16, B*H=64), block 256; each wave owns 16 Q rows (q = l15).
// K/Vt fragments are pre-permuted into lane-linear 16B-chunk layout by k_qkv_conv:
// every hot-loop load is base + lane*16 (fully coalesced b128). No LDS, no barriers,
// no max-subtraction (post-ReLU scores >= 0, bounded).
__global__ __launch_bounds__(256) void k_time_attn(
    const unsigned short* __restrict__ q, const unsigned short* __restrict__ kfrag,
    const unsigned short* __restrict__ vtfrag, unsigned short* __restrict__ vp) {
    int wave = threadIdx.x >> 6, lane = threadIdx.x & 63;
    int l15 = lane & 15, quad = lane >> 4;
    int bh = blockIdx.y;
    int b = bh >> 3, h = bh & 7;
    int qr = blockIdx.x * 64 + wave * 16;
    const short* Q = (const short*)q + (size_t)bh * TT * HDIM;
    const short* KF = (const short*)kfrag + (size_t)bh * 16 * 8 * 512 + lane * 8;
    const short* VF = (const short*)vtfrag + (size_t)bh * 16 * 8 * 512 + lane * 8;

    // Q rows as B-operand of S^T = K.Q^T (n = q = l15)
    short8 bq[2];
#pragma unroll
    for (int kf = 0; kf < 2; ++kf)
        bq[kf] = *(const short8*)(Q + (qr + l15) * HDIM + kf * 32 + quad * 8);

    floatx4 o[4];  // O^T accum: d = df*16 + quad*4 + r, q = l15
#pragma unroll
    for (int df = 0; df < 4; ++df) o[df] = (floatx4){0.f, 0.f, 0.f, 0.f};
    float lacc = 0.f;  // sum of this lane's P values (q = l15)

    for (int sblk = 0; sblk < 16; ++sblk) {
        const short* kp = KF + sblk * 8 * 512;
        const short* vv = VF + sblk * 8 * 512;
        floatx4 c[4];
#pragma unroll
        for (int jr = 0; jr < 4; ++jr) c[jr] = (floatx4){0.f, 0.f, 0.f, 0.f};
#pragma unroll
        for (int jr = 0; jr < 4; ++jr) {
#pragma unroll
            for (int kf = 0; kf < 2; ++kf) {
                short8 ak = *(const short8*)(kp + (jr * 2 + kf) * 512);
                c[jr] = __builtin_amdgcn_mfma_f32_16x16x32_bf16(ak, bq[kf], c[jr], 0, 0, 0);
            }
        }
        // lane (l15,quad) holds s-offsets {quad*8..+7} (c0,c1) and {32+quad*8..+7} (c2,c3):
        // exactly the PV B-fragment. exp + pack in-register.
        short8 pb[2];
#pragma unroll
        for (int kf = 0; kf < 2; ++kf) {
            union { short8 s; unsigned u[4]; } pk;
#pragma unroll
            for (int half = 0; half < 2; ++half) {
                floatx4 cc = c[2 * kf + half];
                float p0 = __expf(cc[0] * 0.125f);
                float p1 = __expf(cc[1] * 0.125f);
                float p2 = __expf(cc[2] * 0.125f);
                float p3 = __expf(cc[3] * 0.125f);
                lacc += (p0 + p1) + (p2 + p3);
                pk.u[half * 2] =
                    __builtin_amdgcn_perm(__float_as_uint(p1), __float_as_uint(p0), 0x07060302u);
                pk.u[half * 2 + 1] =
                    __builtin_amdgcn_perm(__float_as_uint(p3), __float_as_uint(p2), 0x07060302u);
            }
            pb[kf] = pk.s;
        }
        // O^T += Vt . P^T  (A = Vt-frag, B = pb)
#pragma unroll
        for (int df = 0; df < 4; ++df) {
#pragma unroll
            for (int kf = 0; kf < 2; ++kf) {
                short8 av = *(const short8*)(vv + (df * 2 + kf) * 512);
                o[df] = __builtin_amdgcn_mfma_f32_16x16x32_bf16(av, pb[kf], o[df], 0, 0, 0);
            }
        }
    }

    // total l for q=l15: sum across the 4 quads holding this q
    lacc += __shfl_xor(lacc, 16);
    lacc += __shfl_xor(lacc, 32);
    float linv = 1.f / lacc;

    // store O[t=qr+l15][h*64 + df*16 + quad*4 + r] as packed b64
    unsigned short* vrow = vp + (size_t)(b * TP + 1 + qr + l15) * (2 * DD) + h * 64;
#pragma unroll
    for (int df = 0; df < 4; ++df) {
        ushort4 pk;
#pragma unroll
        for (int r = 0; r < 4; ++r) ((unsigned short*)&pk)[r] = f2bf(o[df][r] * linv);
        *(ushort4*)&vrow[df * 16 + quad * 4] = pk;
    }
}

// ---------------- channel attention: Gram partials (4-way T split) ----------------
// grid (4, B*H=64), block 256; wave w owns c-rows [16w,16w+16)
__global__ __launch_bounds__(256) void k_chan_gram(
    const unsigned short* __restrict__ qt, const unsigned short* __restrict__ kt,
    float* __restrict__ gbuf) {
    int wave = threadIdx.x >> 6, lane = threadIdx.x & 63;
    int l15 = lane & 15, quad = lane >> 4;
    int tc = blockIdx.x, bh = blockIdx.y;
    const short* Qt = (const short*)qt + (size_t)bh * HDIM * TT;
    const short* Kt = (const short*)kt + (size_t)bh * HDIM * TT;

    floatx4 g[4];
#pragma unroll
    for (int nt = 0; nt < 4; ++nt) g[nt] = (floatx4){0.f, 0.f, 0.f, 0.f};

    int t0b = tc * 256;
    for (int t0 = 0; t0 < 256; t0 += 32) {
        short8 aq = *(const short8*)(Qt + (wave * 16 + l15) * TT + t0b + t0 + quad * 8);
#pragma unroll
        for (int nt = 0; nt < 4; ++nt) {
            short8 bk = *(const short8*)(Kt + (nt * 16 + l15) * TT + t0b + t0 + quad * 8);
            g[nt] = __builtin_amdgcn_mfma_f32_16x16x32_bf16(aq, bk, g[nt], 0, 0, 0);
        }
    }
    float* gb = gbuf + bh * HDIM * HDIM;
#pragma unroll
    for (int nt = 0; nt < 4; ++nt) {
#pragma unroll
        for (int r = 0; r < 4; ++r) {
            int row = wave * 16 + quad * 4 + r;
            atomicAdd(&gb[row * HDIM + nt * 16 + l15], g[nt][r]);
        }
    }
}

// ---------------- channel attention: softmax + A.V (4-way T split) ----------------
// grid (4, B*H=64), block 256
__global__ __launch_bounds__(256) void k_chan_av(
    const float* __restrict__ gbuf, const unsigned short* __restrict__ v,
    unsigned short* __restrict__ vp) {
    __shared__ short lds_a[64 * 64];
    int wave = threadIdx.x >> 6, lane = threadIdx.x & 63;
    int l15 = lane & 15, quad = lane >> 4;
    int tc = blockIdx.x, bh = blockIdx.y;
    int b = bh >> 3, h = bh & 7;
    const float sc = 0.03125f;  // 1/sqrt(1024)

    if (threadIdx.x < 64) {
        const float* gb = gbuf + bh * HDIM * HDIM + threadIdx.x * HDIM;
        float mx = -3.0e38f;
        for (int j = 0; j < 64; ++j) mx = fmaxf(mx, gb[j] * sc);
        float sum = 0.f;
        for (int j = 0; j < 64; ++j) sum += __expf(gb[j] * sc - mx);
        float inv = 1.f / sum;
        for (int j = 0; j < 64; ++j)
            lds_a[threadIdx.x * 64 + j] = (short)f2bf(__expf(gb[j] * sc - mx) * inv);
    }
    __syncthreads();

    const short* V = (const short*)v + (size_t)bh * TT * HDIM;
    short8 pa[2];
#pragma unroll
    for (int kf = 0; kf < 2; ++kf)
        pa[kf] = *(const short8*)&lds_a[(wave * 16 + l15) * 64 + kf * 32 + quad * 8];

    for (int tt = 0; tt < 16; ++tt) {
        int ttile = tc * 16 + tt;
        floatx4 c = (floatx4){0.f, 0.f, 0.f, 0.f};
#pragma unroll
        for (int kf = 0; kf < 2; ++kf) {
            short8 bv = *(const short8*)(V + (ttile * 16 + l15) * HDIM + kf * 32 + quad * 8);
            c = __builtin_amdgcn_mfma_f32_16x16x32_bf16(pa[kf], bv, c, 0, 0, 0);
        }
        int t = ttile * 16 + l15;
#pragma unroll
        for (int r = 0; r < 4; ++r) {
            int crow = wave * 16 + quad * 4 + r;
            int tout = crow * 16 + (t >> 6);
            int col = 512 + ((t & 63) << 3) + h;
            vp[(b * TP + 1 + tout) * (2 * DD) + col] = f2bf(c[r]);
        }
    }
}

// ---------------- output conv: 128x128 tile, BK=32, LDS staged ----------------
// grid (T/128=8, 512/128=4, B=8)
__global__ __launch_bounds__(256) void k_out_conv(
    const unsigned short* __restrict__ vp, const unsigned short* __restrict__ w2k,
    const float* __restrict__ b2, float* __restrict__ out) {
    __shared__ short As[144 * 32];
    __shared__ short Ws[3 * 128 * 32];
    int wave = threadIdx.x >> 6, lane = threadIdx.x & 63;
    int l15 = lane & 15, quad = lane >> 4;
    int wm = wave >> 1, wn = wave & 1;
    int tb = blockIdx.x * 128;
    int cb = blockIdx.y * 128;
    int b = blockIdx.z;
    const short* A = (const short*)vp + b * TP * DD2;
    const short* W = (const short*)w2k;
    int srow = lane >> 2;
    int scol = (lane & 3) * 8;

    floatx4 acc[4][4];
#pragma unroll
    for (int mi = 0; mi < 4; ++mi)
#pragma unroll
        for (int ni = 0; ni < 4; ++ni) acc[mi][ni] = (floatx4){0.f, 0.f, 0.f, 0.f};

    for (int ci = 0; ci < DD2; ci += 32) {
        if (ci) __syncthreads();
        for (int j = wave; j < 33; j += 4) {
            if (j < 9) {
                gl2lds16(A + (tb + j * 16 + srow) * DD2 + ci + scol, &As[j * 512]);
            } else {
                int jj = j - 9;
                int k = jj >> 3;
                gl2lds16(W + (k * DD + cb + (jj & 7) * 16 + srow) * DD2 + ci + scol,
                         &Ws[jj * 512]);
            }
        }
        __syncthreads();
#pragma unroll
        for (int k = 0; k < 3; ++k) {
            short8 af[4], bf[4];
#pragma unroll
            for (int mi = 0; mi < 4; ++mi)
                af[mi] = *(const short8*)&As[(wm * 64 + mi * 16 + l15 + k) * 32 + quad * 8];
#pragma unroll
            for (int ni = 0; ni < 4; ++ni)
                bf[ni] = *(const short8*)&Ws[(k * 128 + wn * 64 + ni * 16 + l15) * 32 + quad * 8];
#pragma unroll
            for (int mi = 0; mi < 4; ++mi)
#pragma unroll
                for (int ni = 0; ni < 4; ++ni)
                    acc[mi][ni] = __builtin_amdgcn_mfma_f32_16x16x32_bf16(af[mi], bf[ni], acc[mi][ni], 0, 0, 0);
        }
    }

#pragma unroll
    for (int ni = 0; ni < 4; ++ni) {
        int co = cb + wn * 64 + ni * 16 + l15;
        float bv = b2[co];
#pragma unroll
        for (int mi = 0; mi < 4; ++mi) {
#pragma unroll
            for (int r = 0; r < 4; ++r) {
                int t = tb + wm * 64 + mi * 16 + quad * 4 + r;
                out[((size_t)b * TT + t) * DD + co] = fmaxf(acc[mi][ni][r] + bv, 0.f);
            }
        }
    }
}

extern "C" void kernel_launch(void* const* d_in, const int* in_sizes, int n_in,
                              void* d_out, int out_size, void* d_ws, size_t ws_size,
                              hipStream_t stream) {
    const float* x = (const float*)d_in[0];
    const float* w11 = (const float*)d_in[1];
    const float* b11 = (const float*)d_in[2];
    const float* w12 = (const float*)d_in[3];
    const float* b12 = (const float*)d_in[4];
    const float* w13 = (const float*)d_in[5];
    const float* b13 = (const float*)d_in[6];
    const float* w2 = (const float*)d_in[7];
    const float* b2 = (const float*)d_in[8];
    float* out = (float*)d_out;

    char* ws = (char*)d_ws;
    size_t off = 0;
    auto alloc = [&](size_t bytes) {
        void* p = ws + off;
        off += (bytes + 255) & ~(size_t)255;
        return p;
    };
    unsigned short* xp = (unsigned short*)alloc((size_t)BB * TP * DD * 2);
    unsigned short* wqkv = (unsigned short*)alloc((size_t)9 * DD * DD * 2);
    unsigned short* w2k = (unsigned short*)alloc((size_t)3 * DD * DD2 * 2);
    unsigned short* q = (unsigned short*)alloc((size_t)BB * HH * TT * HDIM * 2);
    unsigned short* qt = (unsigned short*)alloc((size_t)BB * HH * TT * HDIM * 2);
    unsigned short* kfrag = (unsigned short*)alloc((size_t)BB * HH * TT * HDIM * 2);
    unsigned short* kt = (unsigned short*)alloc((size_t)BB * HH * TT * HDIM * 2);
    unsigned short* v = (unsigned short*)alloc((size_t)BB * HH * TT * HDIM * 2);
    unsigned short* vtfrag = (unsigned short*)alloc((size_t)BB * HH * TT * HDIM * 2);
    float* gbuf = (float*)alloc((size_t)64 * HDIM * HDIM * 4);
    unsigned short* vp = (unsigned short*)alloc((size_t)BB * TP * 2 * DD * 2);
    (void)alloc(65536);  // guard: halo staging reads up to 14 rows past vp end

    k_convert_x<<<(BB * TP * DD + 255) / 256, 256, 0, stream>>>(x, xp);
    k_convert_wqkv<<<(3 * 3 * DD * DD + 255) / 256, 256, 0, stream>>>(w11, w12, w13, wqkv);
    k_convert_w2<<<(3 * DD * DD2 + 255) / 256, 256, 0, stream>>>(w2, w2k);
    k_zero_aux<<<(64 * HDIM * HDIM + 255) / 256, 256, 0, stream>>>(vp, gbuf);
    k_qkv_conv<<<dim3(TT / 128, DD / 128, BB * 3), 256, 0, stream>>>(xp, wqkv, b11, b12, b13,
                                                                     q, qt, kfrag, kt, v, vtfrag);
    k_time_attn<<<dim3(TT / 64, BB * HH), 256, 0, stream>>>(q, kfrag, vtfrag, vp);
    k_chan_gram<<<dim3(4, BB * HH), 256, 0, stream>>>(qt, kt, gbuf);
    k_chan_av<<<dim3(4, BB * HH), 256, 0, stream>>>(gbuf, v, vp);
    k_out_conv<<<dim3(TT / 128, DD / 128, BB), 256, 0, stream>>>(vp, w2k, b2, out);
}

// Round 7
// 281.157 us; speedup vs baseline: 1.2981x; 1.0253x over previous
//
#include <hip/hip_runtime.h>

#define BB 8
#define TT 1024
#define DD 512
#define DD2 1024
#define HH 8
#define HDIM 64
#define TP (TT + 2)

typedef short short8 __attribute__((ext_vector_type(8)));
typedef float floatx4 __attribute__((ext_vector_type(4)));

typedef const __attribute__((address_space(1))) unsigned int* gas_ptr;
typedef __attribute__((address_space(3))) unsigned int* las_ptr;

__device__ __forceinline__ unsigned short f2bf(float f) {
    union { float f; unsigned u; } v; v.f = f;
    unsigned r = v.u + 0x7fffu + ((v.u >> 16) & 1u);
    return (unsigned short)(r >> 16);
}

// async global->LDS, 16B per lane, LDS dst = wave-uniform base + lane*16
__device__ __forceinline__ void gl2lds16(const void* g, void* l) {
    __builtin_amdgcn_global_load_lds((gas_ptr)g, (las_ptr)l, 16, 0, 0);
}

// ---------------- prep kernels ----------------
__global__ void k_convert_x(const float* __restrict__ x, unsigned short* __restrict__ xp) {
    int idx = blockIdx.x * 256 + threadIdx.x;
    const int total = BB * TP * DD;
    if (idx >= total) return;
    int c = idx % DD;
    int rt = idx / DD;
    int row = rt % TP;
    int b = rt / TP;
    float v = 0.f;
    if (row >= 1 && row <= TT) v = x[(b * TT + row - 1) * DD + c];
    xp[idx] = f2bf(v);
}

__global__ void k_convert_wqkv(const float* __restrict__ w0, const float* __restrict__ w1,
                               const float* __restrict__ w2, unsigned short* __restrict__ out) {
    int idx = blockIdx.x * 256 + threadIdx.x;
    const int total = 3 * 3 * DD * DD;
    if (idx >= total) return;
    int ci = idx % DD;
    int t1 = idx / DD;
    int co = t1 % DD;
    int t2 = t1 / DD;
    int k = t2 % 3;
    int p = t2 / 3;
    const float* w = (p == 0) ? w0 : ((p == 1) ? w1 : w2);
    out[idx] = f2bf(w[(co * DD + ci) * 3 + k]);
}

__global__ void k_convert_w2(const float* __restrict__ w, unsigned short* __restrict__ out) {
    int idx = blockIdx.x * 256 + threadIdx.x;
    const int total = 3 * DD * DD2;
    if (idx >= total) return;
    int ci = idx % DD2;
    int t1 = idx / DD2;
    int co = t1 % DD;
    int k = t1 / DD;
    out[idx] = f2bf(w[(co * DD2 + ci) * 3 + k]);
}

__global__ void k_zero_aux(unsigned short* __restrict__ vp, float* __restrict__ gbuf) {
    int idx = blockIdx.x * 256 + threadIdx.x;
    if (idx < BB * 2 * 2 * DD) {
        int c = idx % (2 * DD);
        int t1 = idx / (2 * DD);
        int row = (t1 & 1) ? (TT + 1) : 0;
        int b = t1 >> 1;
        vp[(b * TP + row) * (2 * DD) + c] = 0;
    }
    if (idx < 64 * HDIM * HDIM) gbuf[idx] = 0.f;
}

// ---------------- QKV conv: 128x128 tile, BK=32, LDS staged + XOR bank swizzle --------
// grid (T/128=8, 512/128=4, B*3=24), 256 thr = 4 waves (2x2), wave tile 64x64.
// LDS chunk swizzle: slot (row, cs) holds global chunk cs ^ (row&3)  -> frag reads 2-way (free).
__global__ __launch_bounds__(256) void k_qkv_conv(
    const unsigned short* __restrict__ xp, const unsigned short* __restrict__ wqkv,
    const float* __restrict__ b11, const float* __restrict__ b12, const float* __restrict__ b13,
    unsigned short* __restrict__ q, unsigned short* __restrict__ qt,
    unsigned short* __restrict__ kfrag, unsigned short* __restrict__ kt,
    unsigned short* __restrict__ v, unsigned short* __restrict__ vtfrag) {
    __shared__ short As[144 * 32];      // rows tb..tb+143 (halo; only 0..129 used)
    __shared__ short Ws[3 * 128 * 32];  // [k][co 128][ci 32]
    int wave = threadIdx.x >> 6, lane = threadIdx.x & 63;
    int l15 = lane & 15, quad = lane >> 4;
    int wm = wave >> 1, wn = wave & 1;
    int tb = blockIdx.x * 128;
    int cb = blockIdx.y * 128;
    int proj = blockIdx.z % 3, b = blockIdx.z / 3;
    const short* A = (const short*)xp + b * TP * DD;
    const short* W = (const short*)wqkv + proj * 3 * DD * DD;
    int srow = lane >> 2;                            // staging: lane -> row 0..15
    int scs = (((lane & 3) ^ (srow & 3)) << 3);      // swizzled source chunk (8 shorts)

    floatx4 acc[4][4];
#pragma unroll
    for (int mi = 0; mi < 4; ++mi)
#pragma unroll
        for (int ni = 0; ni < 4; ++ni) acc[mi][ni] = (floatx4){0.f, 0.f, 0.f, 0.f};

    for (int ci = 0; ci < DD; ci += 32) {
        if (ci) __syncthreads();
        for (int j = wave; j < 33; j += 4) {
            if (j < 9) {
                gl2lds16(A + (tb + j * 16 + srow) * DD + ci + scs, &As[j * 512]);
            } else {
                int jj = j - 9;
                int k = jj >> 3;
                gl2lds16(W + k * DD * DD + (cb + (jj & 7) * 16 + srow) * DD + ci + scs,
                         &Ws[jj * 512]);
            }
        }
        __syncthreads();
#pragma unroll
        for (int k = 0; k < 3; ++k) {
            short8 af[4], bf[4];
#pragma unroll
            for (int mi = 0; mi < 4; ++mi) {
                int arow = wm * 64 + mi * 16 + l15 + k;
                af[mi] = *(const short8*)&As[arow * 32 + ((quad ^ (arow & 3)) << 3)];
            }
#pragma unroll
            for (int ni = 0; ni < 4; ++ni) {
                int brow = wn * 64 + ni * 16 + l15;
                bf[ni] = *(const short8*)&Ws[(k * 128 + brow) * 32 + ((quad ^ (l15 & 3)) << 3)];
            }
#pragma unroll
            for (int mi = 0; mi < 4; ++mi)
#pragma unroll
                for (int ni = 0; ni < 4; ++ni)
                    acc[mi][ni] = __builtin_amdgcn_mfma_f32_16x16x32_bf16(af[mi], bf[ni], acc[mi][ni], 0, 0, 0);
        }
    }

    const float* bias = (proj == 0) ? b11 : ((proj == 1) ? b12 : b13);
#pragma unroll
    for (int ni = 0; ni < 4; ++ni) {
        int co = cb + wn * 64 + ni * 16 + l15;
        float bv = bias[co];
        int h = co >> 6, hd = co & 63;
        int bh = b * HH + h;
#pragma unroll
        for (int mi = 0; mi < 4; ++mi) {
            int tbase = tb + wm * 64 + mi * 16 + quad * 4;
            unsigned short bb[4];
            ushort4 pk;
#pragma unroll
            for (int r = 0; r < 4; ++r) {
                float val = fmaxf(acc[mi][ni][r] + bv, 0.f);
                bb[r] = f2bf(val);
                ((unsigned short*)&pk)[r] = bb[r];
            }
            if (proj == 0) {
#pragma unroll
                for (int r = 0; r < 4; ++r)
                    q[((size_t)bh * TT + tbase + r) * HDIM + hd] = bb[r];
                *(ushort4*)&qt[((size_t)bh * HDIM + hd) * TT + tbase] = pk;
            } else if (proj == 1) {
                *(ushort4*)&kt[((size_t)bh * HDIM + hd) * TT + tbase] = pk;
                // K-frag layout: [bh][sblk][jr][kf][quad_a*16+l15a][8]
                int sblk = tbase >> 6;
                int jr = (quad & 1) + 2 * (mi >> 1);
                int l15a_base = 4 * (quad >> 1) + 8 * (mi & 1);  // + r
                int kf = hd >> 5, quad_a = (hd >> 3) & 3, elem = hd & 7;
                size_t base = ((((size_t)bh * 16 + sblk) * 4 + jr) * 2 + kf) * 512 +
                              quad_a * 128 + elem;
#pragma unroll
                for (int r = 0; r < 4; ++r)
                    kfrag[base + (l15a_base + r) * 8] = bb[r];
            } else {
#pragma unroll
                for (int r = 0; r < 4; ++r)
                    v[((size_t)bh * TT + tbase + r) * HDIM + hd] = bb[r];
                // Vt-frag layout: [bh][sblk][df][kf][quad_a*16+l15a][8]
                int sblk = tbase >> 6;
                int df = hd >> 4, l15a = hd & 15;
                int kf = mi >> 1;
                int quad_a = 2 * (mi & 1) + (quad >> 1);
                int elem = (quad & 1) * 4;
                size_t base = ((((size_t)bh * 16 + sblk) * 4 + df) * 2 + kf) * 512 +
                              (quad_a * 16 + l15a) * 8 + elem;
                *(ushort4*)&vtfrag[base] = pk;
            }
        }
    }
}

// ---------------- time attention: all-register flash, lane-linear frag loads ----------
// grid (T/64=16, B*H=64), block 256; each wave owns 16 Q rows (q = l15).
__global__ __launch_bounds__(256) void k_time_attn(
    const unsigned short* __restrict__ q, const unsigned short* __restrict__ kfrag,
    const unsigned short* __restrict__ vtfrag, unsigned short* __restrict__ vp) {
    int wave = threadIdx.x >> 6, lane = threadIdx.x & 63;
    int l15 = lane & 15, quad = lane >> 4;
    int bh = blockIdx.y;
    int b = bh >> 3, h = bh & 7;
    int qr = blockIdx.x * 64 + wave * 16;
    const short* Q = (const short*)q + (size_t)bh * TT * HDIM;
    const short* KF = (const short*)kfrag + (size_t)bh * 16 * 8 * 512 + lane * 8;
    const short* VF = (const short*)vtfrag + (size_t)bh * 16 * 8 * 512 + lane * 8;

    short8 bq[2];
#pragma unroll
    for (int kf = 0; kf < 2; ++kf)
        bq[kf] = *(const short8*)(Q + (qr + l15) * HDIM + kf * 32 + quad * 8);

    floatx4 o[4];  // O^T accum: d = df*16 + quad*4 + r, q = l15
#pragma unroll
    for (int df = 0; df < 4; ++df) o[df] = (floatx4){0.f, 0.f, 0.f, 0.f};
    float lacc = 0.f;

    for (int sblk = 0; sblk < 16; ++sblk) {
        const short* kp = KF + sblk * 8 * 512;
        const short* vv = VF + sblk * 8 * 512;
        floatx4 c[4];
#pragma unroll
        for (int jr = 0; jr < 4; ++jr) c[jr] = (floatx4){0.f, 0.f, 0.f, 0.f};
#pragma unroll
        for (int jr = 0; jr < 4; ++jr) {
#pragma unroll
            for (int kf = 0; kf < 2; ++kf) {
                short8 ak = *(const short8*)(kp + (jr * 2 + kf) * 512);
                c[jr] = __builtin_amdgcn_mfma_f32_16x16x32_bf16(ak, bq[kf], c[jr], 0, 0, 0);
            }
        }
        short8 pb[2];
#pragma unroll
        for (int kf = 0; kf < 2; ++kf) {
            union { short8 s; unsigned u[4]; } pk;
#pragma unroll
            for (int half = 0; half < 2; ++half) {
                floatx4 cc = c[2 * kf + half];
                float p0 = __expf(cc[0] * 0.125f);
                float p1 = __expf(cc[1] * 0.125f);
                float p2 = __expf(cc[2] * 0.125f);
                float p3 = __expf(cc[3] * 0.125f);
                lacc += (p0 + p1) + (p2 + p3);
                pk.u[half * 2] =
                    __builtin_amdgcn_perm(__float_as_uint(p1), __float_as_uint(p0), 0x07060302u);
                pk.u[half * 2 + 1] =
                    __builtin_amdgcn_perm(__float_as_uint(p3), __float_as_uint(p2), 0x07060302u);
            }
            pb[kf] = pk.s;
        }
#pragma unroll
        for (int df = 0; df < 4; ++df) {
#pragma unroll
            for (int kf = 0; kf < 2; ++kf) {
                short8 av = *(const short8*)(vv + (df * 2 + kf) * 512);
                o[df] = __builtin_amdgcn_mfma_f32_16x16x32_bf16(av, pb[kf], o[df], 0, 0, 0);
            }
        }
    }

    lacc += __shfl_xor(lacc, 16);
    lacc += __shfl_xor(lacc, 32);
    float linv = 1.f / lacc;

    unsigned short* vrow = vp + (size_t)(b * TP + 1 + qr + l15) * (2 * DD) + h * 64;
#pragma unroll
    for (int df = 0; df < 4; ++df) {
        ushort4 pk;
#pragma unroll
        for (int r = 0; r < 4; ++r) ((unsigned short*)&pk)[r] = f2bf(o[df][r] * linv);
        *(ushort4*)&vrow[df * 16 + quad * 4] = pk;
    }
}

// ---------------- channel attention: Gram partials (4-way T split) ----------------
__global__ __launch_bounds__(256) void k_chan_gram(
    const unsigned short* __restrict__ qt, const unsigned short* __restrict__ kt,
    float* __restrict__ gbuf) {
    int wave = threadIdx.x >> 6, lane = threadIdx.x & 63;
    int l15 = lane & 15, quad = lane >> 4;
    int tc = blockIdx.x, bh = blockIdx.y;
    const short* Qt = (const short*)qt + (size_t)bh * HDIM * TT;
    const short* Kt = (const short*)kt + (size_t)bh * HDIM * TT;

    floatx4 g[4];
#pragma unroll
    for (int nt = 0; nt < 4; ++nt) g[nt] = (floatx4){0.f, 0.f, 0.f, 0.f};

    int t0b = tc * 256;
    for (int t0 = 0; t0 < 256; t0 += 32) {
        short8 aq = *(const short8*)(Qt + (wave * 16 + l15) * TT + t0b + t0 + quad * 8);
#pragma unroll
        for (int nt = 0; nt < 4; ++nt) {
            short8 bk = *(const short8*)(Kt + (nt * 16 + l15) * TT + t0b + t0 + quad * 8);
            g[nt] = __builtin_amdgcn_mfma_f32_16x16x32_bf16(aq, bk, g[nt], 0, 0, 0);
        }
    }
    float* gb = gbuf + bh * HDIM * HDIM;
#pragma unroll
    for (int nt = 0; nt < 4; ++nt) {
#pragma unroll
        for (int r = 0; r < 4; ++r) {
            int row = wave * 16 + quad * 4 + r;
            atomicAdd(&gb[row * HDIM + nt * 16 + l15], g[nt][r]);
        }
    }
}

// ---------------- channel attention: softmax + A.V (4-way T split) ----------------
__global__ __launch_bounds__(256) void k_chan_av(
    const float* __restrict__ gbuf, const unsigned short* __restrict__ v,
    unsigned short* __restrict__ vp) {
    __shared__ short lds_a[64 * 64];
    int wave = threadIdx.x >> 6, lane = threadIdx.x & 63;
    int l15 = lane & 15, quad = lane >> 4;
    int tc = blockIdx.x, bh = blockIdx.y;
    int b = bh >> 3, h = bh & 7;
    const float sc = 0.03125f;  // 1/sqrt(1024)

    if (threadIdx.x < 64) {
        const float* gb = gbuf + bh * HDIM * HDIM + threadIdx.x * HDIM;
        float mx = -3.0e38f;
        for (int j = 0; j < 64; ++j) mx = fmaxf(mx, gb[j] * sc);
        float sum = 0.f;
        for (int j = 0; j < 64; ++j) sum += __expf(gb[j] * sc - mx);
        float inv = 1.f / sum;
        for (int j = 0; j < 64; ++j)
            lds_a[threadIdx.x * 64 + j] = (short)f2bf(__expf(gb[j] * sc - mx) * inv);
    }
    __syncthreads();

    const short* V = (const short*)v + (size_t)bh * TT * HDIM;
    short8 pa[2];
#pragma unroll
    for (int kf = 0; kf < 2; ++kf)
        pa[kf] = *(const short8*)&lds_a[(wave * 16 + l15) * 64 + kf * 32 + quad * 8];

    for (int tt = 0; tt < 16; ++tt) {
        int ttile = tc * 16 + tt;
        floatx4 c = (floatx4){0.f, 0.f, 0.f, 0.f};
#pragma unroll
        for (int kf = 0; kf < 2; ++kf) {
            short8 bv = *(const short8*)(V + (ttile * 16 + l15) * HDIM + kf * 32 + quad * 8);
            c = __builtin_amdgcn_mfma_f32_16x16x32_bf16(pa[kf], bv, c, 0, 0, 0);
        }
        int t = ttile * 16 + l15;
#pragma unroll
        for (int r = 0; r < 4; ++r) {
            int crow = wave * 16 + quad * 4 + r;
            int tout = crow * 16 + (t >> 6);
            int col = 512 + ((t & 63) << 3) + h;
            vp[(b * TP + 1 + tout) * (2 * DD) + col] = f2bf(c[r]);
        }
    }
}

// ---------------- output conv: 128x64 tile, BK=32, LDS staged + XOR swizzle ----------
// grid (T/128=8, 512/64=8, B=8) = 512 blocks (2/CU). 4 waves as 2x2, wave tile 64x32.
__global__ __launch_bounds__(256) void k_out_conv(
    const unsigned short* __restrict__ vp, const unsigned short* __restrict__ w2k,
    const float* __restrict__ b2, float* __restrict__ out) {
    __shared__ short As[144 * 32];
    __shared__ short Ws[3 * 64 * 32];  // [k][co 64][ci 32]
    int wave = threadIdx.x >> 6, lane = threadIdx.x & 63;
    int l15 = lane & 15, quad = lane >> 4;
    int wm = wave >> 1, wn = wave & 1;
    int tb = blockIdx.x * 128;
    int cb = blockIdx.y * 64;
    int b = blockIdx.z;
    const short* A = (const short*)vp + b * TP * DD2;
    const short* W = (const short*)w2k;
    int srow = lane >> 2;
    int scs = (((lane & 3) ^ (srow & 3)) << 3);

    floatx4 acc[4][2];
#pragma unroll
    for (int mi = 0; mi < 4; ++mi)
#pragma unroll
        for (int ni = 0; ni < 2; ++ni) acc[mi][ni] = (floatx4){0.f, 0.f, 0.f, 0.f};

    for (int ci = 0; ci < DD2; ci += 32) {
        if (ci) __syncthreads();
        for (int j = wave; j < 21; j += 4) {
            if (j < 9) {
                gl2lds16(A + (tb + j * 16 + srow) * DD2 + ci + scs, &As[j * 512]);
            } else {
                int jj = j - 9;
                int k = jj >> 2;
                gl2lds16(W + (k * DD + cb + (jj & 3) * 16 + srow) * DD2 + ci + scs,
                         &Ws[jj * 512]);
            }
        }
        __syncthreads();
#pragma unroll
        for (int k = 0; k < 3; ++k) {
            short8 af[4], bf[2];
#pragma unroll
            for (int mi = 0; mi < 4; ++mi) {
                int arow = wm * 64 + mi * 16 + l15 + k;
                af[mi] = *(const short8*)&As[arow * 32 + ((quad ^ (arow & 3)) << 3)];
            }
#pragma unroll
            for (int ni = 0; ni < 2; ++ni) {
                int brow = wn * 32 + ni * 16 + l15;
                bf[ni] = *(const short8*)&Ws[(k * 64 + brow) * 32 + ((quad ^ (l15 & 3)) << 3)];
            }
#pragma unroll
            for (int mi = 0; mi < 4; ++mi)
#pragma unroll
                for (int ni = 0; ni < 2; ++ni)
                    acc[mi][ni] = __builtin_amdgcn_mfma_f32_16x16x32_bf16(af[mi], bf[ni], acc[mi][ni], 0, 0, 0);
        }
    }

#pragma unroll
    for (int ni = 0; ni < 2; ++ni) {
        int co = cb + wn * 32 + ni * 16 + l15;
        float bv = b2[co];
#pragma unroll
        for (int mi = 0; mi < 4; ++mi) {
#pragma unroll
            for (int r = 0; r < 4; ++r) {
                int t = tb + wm * 64 + mi * 16 + quad * 4 + r;
                out[((size_t)b * TT + t) * DD + co] = fmaxf(acc[mi][ni][r] + bv, 0.f);
            }
        }
    }
}

extern "C" void kernel_launch(void* const* d_in, const int* in_sizes, int n_in,
                              void* d_out, int out_size, void* d_ws, size_t ws_size,
                              hipStream_t stream) {
    const float* x = (const float*)d_in[0];
    const float* w11 = (const float*)d_in[1];
    const float* b11 = (const float*)d_in[2];
    const float* w12 = (const float*)d_in[3];
    const float* b12 = (const float*)d_in[4];
    const float* w13 = (const float*)d_in[5];
    const float* b13 = (const float*)d_in[6];
    const float* w2 = (const float*)d_in[7];
    const float* b2 = (const float*)d_in[8];
    float* out = (float*)d_out;

    char* ws = (char*)d_ws;
    size_t off = 0;
    auto alloc = [&](size_t bytes) {
        void* p = ws + off;
        off += (bytes + 255) & ~(size_t)255;
        return p;
    };
    unsigned short* xp = (unsigned short*)alloc((size_t)BB * TP * DD * 2);
    unsigned short* wqkv = (unsigned short*)alloc((size_t)9 * DD * DD * 2);
    unsigned short* w2k = (unsigned short*)alloc((size_t)3 * DD * DD2 * 2);
    unsigned short* q = (unsigned short*)alloc((size_t)BB * HH * TT * HDIM * 2);
    unsigned short* qt = (unsigned short*)alloc((size_t)BB * HH * TT * HDIM * 2);
    unsigned short* kfrag = (unsigned short*)alloc((size_t)BB * HH * TT * HDIM * 2);
    unsigned short* kt = (unsigned short*)alloc((size_t)BB * HH * TT * HDIM * 2);
    unsigned short* v = (unsigned short*)alloc((size_t)BB * HH * TT * HDIM * 2);
    unsigned short* vtfrag = (unsigned short*)alloc((size_t)BB * HH * TT * HDIM * 2);
    float* gbuf = (float*)alloc((size_t)64 * HDIM * HDIM * 4);
    unsigned short* vp = (unsigned short*)alloc((size_t)BB * TP * 2 * DD * 2);
    (void)alloc(65536);  // guard: halo staging reads up to 14 rows past vp end

    k_convert_x<<<(BB * TP * DD + 255) / 256, 256, 0, stream>>>(x, xp);
    k_convert_wqkv<<<(3 * 3 * DD * DD + 255) / 256, 256, 0, stream>>>(w11, w12, w13, wqkv);
    k_convert_w2<<<(3 * DD * DD2 + 255) / 256, 256, 0, stream>>>(w2, w2k);
    k_zero_aux<<<(64 * HDIM * HDIM + 255) / 256, 256, 0, stream>>>(vp, gbuf);
    k_qkv_conv<<<dim3(TT / 128, DD / 128, BB * 3), 256, 0, stream>>>(xp, wqkv, b11, b12, b13,
                                                                     q, qt, kfrag, kt, v, vtfrag);
    k_time_attn<<<dim3(TT / 64, BB * HH), 256, 0, stream>>>(q, kfrag, vtfrag, vp);
    k_chan_gram<<<dim3(4, BB * HH), 256, 0, stream>>>(qt, kt, gbuf);
    k_chan_av<<<dim3(4, BB * HH), 256, 0, stream>>>(gbuf, v, vp);
    k_out_conv<<<dim3(TT / 128, DD / 64, BB), 256, 0, stream>>>(vp, w2k, b2, out);
}

// Round 8
// 264.001 us; speedup vs baseline: 1.3824x; 1.0650x over previous
//
#include <hip/hip_runtime.h>

#define BB 8
#define TT 1024
#define DD 512
#define DD2 1024
#define HH 8
#define HDIM 64
#define TP (TT + 2)

typedef short short8 __attribute__((ext_vector_type(8)));
typedef float floatx4 __attribute__((ext_vector_type(4)));

typedef const __attribute__((address_space(1))) unsigned int* gas_ptr;
typedef __attribute__((address_space(3))) unsigned int* las_ptr;

__device__ __forceinline__ unsigned short f2bf(float f) {
    union { float f; unsigned u; } v; v.f = f;
    unsigned r = v.u + 0x7fffu + ((v.u >> 16) & 1u);
    return (unsigned short)(r >> 16);
}

// async global->LDS, 16B per lane, LDS dst = wave-uniform base + lane*16
__device__ __forceinline__ void gl2lds16(const void* g, void* l) {
    __builtin_amdgcn_global_load_lds((gas_ptr)g, (las_ptr)l, 16, 0, 0);
}

// ---------------- prep kernels ----------------
__global__ void k_convert_x(const float* __restrict__ x, unsigned short* __restrict__ xp) {
    int idx = blockIdx.x * 256 + threadIdx.x;
    const int total = BB * TP * DD;
    if (idx >= total) return;
    int c = idx % DD;
    int rt = idx / DD;
    int row = rt % TP;
    int b = rt / TP;
    float v = 0.f;
    if (row >= 1 && row <= TT) v = x[(b * TT + row - 1) * DD + c];
    xp[idx] = f2bf(v);
}

// W(qkv) in B-fragment-major layout: [proj][k][ci0(16)][co0(32)][lane(64)][e(8)]
// frag for (k,ci0,co0): lane(l15,quad) holds Wk[co0*16+l15][ci0*32+quad*8+e]
__global__ void k_convert_wqkv(const float* __restrict__ w0, const float* __restrict__ w1,
                               const float* __restrict__ w2, unsigned short* __restrict__ out) {
    int idx = blockIdx.x * 256 + threadIdx.x;
    const int total = 9 << 18;
    if (idx >= total) return;
    int e = idx & 7;
    int lane = (idx >> 3) & 63;
    int co0 = (idx >> 9) & 31;
    int ci0 = (idx >> 14) & 15;
    int rest = idx >> 18;
    int k = rest % 3, p = rest / 3;
    int co = co0 * 16 + (lane & 15);
    int ci = ci0 * 32 + (lane >> 4) * 8 + e;
    const float* w = (p == 0) ? w0 : ((p == 1) ? w1 : w2);
    out[idx] = f2bf(w[(co * DD + ci) * 3 + k]);
}

// W2 in B-fragment-major layout: [k][ci0(32)][co0(32)][lane(64)][e(8)]
__global__ void k_convert_w2(const float* __restrict__ w, unsigned short* __restrict__ out) {
    int idx = blockIdx.x * 256 + threadIdx.x;
    const int total = 3 << 19;
    if (idx >= total) return;
    int e = idx & 7;
    int lane = (idx >> 3) & 63;
    int co0 = (idx >> 9) & 31;
    int ci0 = (idx >> 14) & 31;
    int k = idx >> 19;
    int co = co0 * 16 + (lane & 15);
    int ci = ci0 * 32 + (lane >> 4) * 8 + e;
    out[idx] = f2bf(w[(co * DD2 + ci) * 3 + k]);
}

__global__ void k_zero_aux(unsigned short* __restrict__ vp, float* __restrict__ gbuf) {
    int idx = blockIdx.x * 256 + threadIdx.x;
    if (idx < BB * 2 * 2 * DD) {
        int c = idx % (2 * DD);
        int t1 = idx / (2 * DD);
        int row = (t1 & 1) ? (TT + 1) : 0;
        int b = t1 >> 1;
        vp[(b * TP + row) * (2 * DD) + c] = 0;
    }
    if (idx < 64 * HDIM * HDIM) gbuf[idx] = 0.f;
}

// ---------------- QKV conv: A-only LDS dbuf (9 KB/buf), W streamed frag-major ---------
// grid (T/128=8, 512/128=4, B*3=24), 256 thr = 4 waves (2x2), wave tile 64x64.
__global__ __launch_bounds__(256) void k_qkv_conv(
    const unsigned short* __restrict__ xp, const unsigned short* __restrict__ wfrag,
    const float* __restrict__ b11, const float* __restrict__ b12, const float* __restrict__ b13,
    unsigned short* __restrict__ q, unsigned short* __restrict__ qt,
    unsigned short* __restrict__ kfrag, unsigned short* __restrict__ kt,
    unsigned short* __restrict__ v, unsigned short* __restrict__ vtfrag) {
    __shared__ short As[2][144 * 32];
    int wave = threadIdx.x >> 6, lane = threadIdx.x & 63;
    int l15 = lane & 15, quad = lane >> 4;
    int wm = wave >> 1, wn = wave & 1;
    int tb = blockIdx.x * 128;
    int cb = blockIdx.y * 128;
    int proj = blockIdx.z % 3, b = blockIdx.z / 3;
    const short* A = (const short*)xp + b * TP * DD;
    const short* WF = (const short*)wfrag + (size_t)proj * 786432 + lane * 8;
    int srow = lane >> 2;
    int scs = (((lane & 3) ^ (srow & 3)) << 3);
    int co0b = (cb >> 4) + wn * 4;

    floatx4 acc[4][4];
#pragma unroll
    for (int mi = 0; mi < 4; ++mi)
#pragma unroll
        for (int ni = 0; ni < 4; ++ni) acc[mi][ni] = (floatx4){0.f, 0.f, 0.f, 0.f};

    for (int j = wave; j < 9; j += 4)
        gl2lds16(A + (tb + j * 16 + srow) * DD + scs, &As[0][j * 512]);
    __syncthreads();

    for (int it = 0; it < 16; ++it) {
        if (it < 15) {
            for (int j = wave; j < 9; j += 4)
                gl2lds16(A + (tb + j * 16 + srow) * DD + (it + 1) * 32 + scs,
                         &As[(it + 1) & 1][j * 512]);
        }
        const short* Asb = As[it & 1];
        short8 bf[3][4];
#pragma unroll
        for (int k = 0; k < 3; ++k)
#pragma unroll
            for (int ni = 0; ni < 4; ++ni)
                bf[k][ni] = *(const short8*)(WF + ((size_t)((k * 16 + it) * 32 + co0b + ni) << 9));
#pragma unroll
        for (int k = 0; k < 3; ++k) {
            short8 af[4];
#pragma unroll
            for (int mi = 0; mi < 4; ++mi) {
                int arow = wm * 64 + mi * 16 + l15 + k;
                af[mi] = *(const short8*)&Asb[arow * 32 + ((quad ^ (arow & 3)) << 3)];
            }
#pragma unroll
            for (int mi = 0; mi < 4; ++mi)
#pragma unroll
                for (int ni = 0; ni < 4; ++ni)
                    acc[mi][ni] = __builtin_amdgcn_mfma_f32_16x16x32_bf16(af[mi], bf[k][ni], acc[mi][ni], 0, 0, 0);
        }
        __syncthreads();
    }

    const float* bias = (proj == 0) ? b11 : ((proj == 1) ? b12 : b13);
#pragma unroll
    for (int ni = 0; ni < 4; ++ni) {
        int co = cb + wn * 64 + ni * 16 + l15;
        float bv = bias[co];
        int h = co >> 6, hd = co & 63;
        int bh = b * HH + h;
#pragma unroll
        for (int mi = 0; mi < 4; ++mi) {
            int tbase = tb + wm * 64 + mi * 16 + quad * 4;
            unsigned short bb[4];
            ushort4 pk;
#pragma unroll
            for (int r = 0; r < 4; ++r) {
                float val = fmaxf(acc[mi][ni][r] + bv, 0.f);
                bb[r] = f2bf(val);
                ((unsigned short*)&pk)[r] = bb[r];
            }
            if (proj == 0) {
#pragma unroll
                for (int r = 0; r < 4; ++r)
                    q[((size_t)bh * TT + tbase + r) * HDIM + hd] = bb[r];
                *(ushort4*)&qt[((size_t)bh * HDIM + hd) * TT + tbase] = pk;
            } else if (proj == 1) {
                *(ushort4*)&kt[((size_t)bh * HDIM + hd) * TT + tbase] = pk;
                // K-frag layout: [bh][sblk][jr][kf][quad_a*16+l15a][8]
                int sblk = tbase >> 6;
                int jr = (quad & 1) + 2 * (mi >> 1);
                int l15a_base = 4 * (quad >> 1) + 8 * (mi & 1);  // + r
                int kf = hd >> 5, quad_a = (hd >> 3) & 3, elem = hd & 7;
                size_t base = ((((size_t)bh * 16 + sblk) * 4 + jr) * 2 + kf) * 512 +
                              quad_a * 128 + elem;
#pragma unroll
                for (int r = 0; r < 4; ++r)
                    kfrag[base + (l15a_base + r) * 8] = bb[r];
            } else {
#pragma unroll
                for (int r = 0; r < 4; ++r)
                    v[((size_t)bh * TT + tbase + r) * HDIM + hd] = bb[r];
                // Vt-frag layout: [bh][sblk][df][kf][quad_a*16+l15a][8]
                int sblk = tbase >> 6;
                int df = hd >> 4, l15a = hd & 15;
                int kf = mi >> 1;
                int quad_a = 2 * (mi & 1) + (quad >> 1);
                int elem = (quad & 1) * 4;
                size_t base = ((((size_t)bh * 16 + sblk) * 4 + df) * 2 + kf) * 512 +
                              (quad_a * 16 + l15a) * 8 + elem;
                *(ushort4*)&vtfrag[base] = pk;
            }
        }
    }
}

// ---------------- time attention: all-register flash, lane-linear frag loads ----------
// grid (T/64=16, B*H=64), block 256; each wave owns 16 Q rows (q = l15).
__global__ __launch_bounds__(256) void k_time_attn(
    const unsigned short* __restrict__ q, const unsigned short* __restrict__ kfrag,
    const unsigned short* __restrict__ vtfrag, unsigned short* __restrict__ vp) {
    int wave = threadIdx.x >> 6, lane = threadIdx.x & 63;
    int l15 = lane & 15, quad = lane >> 4;
    int bh = blockIdx.y;
    int b = bh >> 3, h = bh & 7;
    int qr = blockIdx.x * 64 + wave * 16;
    const short* Q = (const short*)q + (size_t)bh * TT * HDIM;
    const short* KF = (const short*)kfrag + (size_t)bh * 16 * 8 * 512 + lane * 8;
    const short* VF = (const short*)vtfrag + (size_t)bh * 16 * 8 * 512 + lane * 8;

    short8 bq[2];
#pragma unroll
    for (int kf = 0; kf < 2; ++kf)
        bq[kf] = *(const short8*)(Q + (qr + l15) * HDIM + kf * 32 + quad * 8);

    floatx4 o[4];  // O^T accum: d = df*16 + quad*4 + r, q = l15
#pragma unroll
    for (int df = 0; df < 4; ++df) o[df] = (floatx4){0.f, 0.f, 0.f, 0.f};
    float lacc = 0.f;

    for (int sblk = 0; sblk < 16; ++sblk) {
        const short* kp = KF + sblk * 8 * 512;
        const short* vv = VF + sblk * 8 * 512;
        floatx4 c[4];
#pragma unroll
        for (int jr = 0; jr < 4; ++jr) c[jr] = (floatx4){0.f, 0.f, 0.f, 0.f};
#pragma unroll
        for (int jr = 0; jr < 4; ++jr) {
#pragma unroll
            for (int kf = 0; kf < 2; ++kf) {
                short8 ak = *(const short8*)(kp + (jr * 2 + kf) * 512);
                c[jr] = __builtin_amdgcn_mfma_f32_16x16x32_bf16(ak, bq[kf], c[jr], 0, 0, 0);
            }
        }
        short8 pb[2];
#pragma unroll
        for (int kf = 0; kf < 2; ++kf) {
            union { short8 s; unsigned u[4]; } pk;
#pragma unroll
            for (int half = 0; half < 2; ++half) {
                floatx4 cc = c[2 * kf + half];
                float p0 = __expf(cc[0] * 0.125f);
                float p1 = __expf(cc[1] * 0.125f);
                float p2 = __expf(cc[2] * 0.125f);
                float p3 = __expf(cc[3] * 0.125f);
                lacc += (p0 + p1) + (p2 + p3);
                pk.u[half * 2] =
                    __builtin_amdgcn_perm(__float_as_uint(p1), __float_as_uint(p0), 0x07060302u);
                pk.u[half * 2 + 1] =
                    __builtin_amdgcn_perm(__float_as_uint(p3), __float_as_uint(p2), 0x07060302u);
            }
            pb[kf] = pk.s;
        }
#pragma unroll
        for (int df = 0; df < 4; ++df) {
#pragma unroll
            for (int kf = 0; kf < 2; ++kf) {
                short8 av = *(const short8*)(vv + (df * 2 + kf) * 512);
                o[df] = __builtin_amdgcn_mfma_f32_16x16x32_bf16(av, pb[kf], o[df], 0, 0, 0);
            }
        }
    }

    lacc += __shfl_xor(lacc, 16);
    lacc += __shfl_xor(lacc, 32);
    float linv = 1.f / lacc;

    unsigned short* vrow = vp + (size_t)(b * TP + 1 + qr + l15) * (2 * DD) + h * 64;
#pragma unroll
    for (int df = 0; df < 4; ++df) {
        ushort4 pk;
#pragma unroll
        for (int r = 0; r < 4; ++r) ((unsigned short*)&pk)[r] = f2bf(o[df][r] * linv);
        *(ushort4*)&vrow[df * 16 + quad * 4] = pk;
    }
}

// ---------------- channel attention: Gram partials (4-way T split) ----------------
__global__ __launch_bounds__(256) void k_chan_gram(
    const unsigned short* __restrict__ qt, const unsigned short* __restrict__ kt,
    float* __restrict__ gbuf) {
    int wave = threadIdx.x >> 6, lane = threadIdx.x & 63;
    int l15 = lane & 15, quad = lane >> 4;
    int tc = blockIdx.x, bh = blockIdx.y;
    const short* Qt = (const short*)qt + (size_t)bh * HDIM * TT;
    const short* Kt = (const short*)kt + (size_t)bh * HDIM * TT;

    floatx4 g[4];
#pragma unroll
    for (int nt = 0; nt < 4; ++nt) g[nt] = (floatx4){0.f, 0.f, 0.f, 0.f};

    int t0b = tc * 256;
    for (int t0 = 0; t0 < 256; t0 += 32) {
        short8 aq = *(const short8*)(Qt + (wave * 16 + l15) * TT + t0b + t0 + quad * 8);
#pragma unroll
        for (int nt = 0; nt < 4; ++nt) {
            short8 bk = *(const short8*)(Kt + (nt * 16 + l15) * TT + t0b + t0 + quad * 8);
            g[nt] = __builtin_amdgcn_mfma_f32_16x16x32_bf16(aq, bk, g[nt], 0, 0, 0);
        }
    }
    float* gb = gbuf + bh * HDIM * HDIM;
#pragma unroll
    for (int nt = 0; nt < 4; ++nt) {
#pragma unroll
        for (int r = 0; r < 4; ++r) {
            int row = wave * 16 + quad * 4 + r;
            atomicAdd(&gb[row * HDIM + nt * 16 + l15], g[nt][r]);
        }
    }
}

// ---------------- channel attention: softmax + A.V (4-way T split) ----------------
__global__ __launch_bounds__(256) void k_chan_av(
    const float* __restrict__ gbuf, const unsigned short* __restrict__ v,
    unsigned short* __restrict__ vp) {
    __shared__ short lds_a[64 * 64];
    int wave = threadIdx.x >> 6, lane = threadIdx.x & 63;
    int l15 = lane & 15, quad = lane >> 4;
    int tc = blockIdx.x, bh = blockIdx.y;
    int b = bh >> 3, h = bh & 7;
    const float sc = 0.03125f;  // 1/sqrt(1024)

    if (threadIdx.x < 64) {
        const float* gb = gbuf + bh * HDIM * HDIM + threadIdx.x * HDIM;
        float mx = -3.0e38f;
        for (int j = 0; j < 64; ++j) mx = fmaxf(mx, gb[j] * sc);
        float sum = 0.f;
        for (int j = 0; j < 64; ++j) sum += __expf(gb[j] * sc - mx);
        float inv = 1.f / sum;
        for (int j = 0; j < 64; ++j)
            lds_a[threadIdx.x * 64 + j] = (short)f2bf(__expf(gb[j] * sc - mx) * inv);
    }
    __syncthreads();

    const short* V = (const short*)v + (size_t)bh * TT * HDIM;
    short8 pa[2];
#pragma unroll
    for (int kf = 0; kf < 2; ++kf)
        pa[kf] = *(const short8*)&lds_a[(wave * 16 + l15) * 64 + kf * 32 + quad * 8];

    for (int tt = 0; tt < 16; ++tt) {
        int ttile = tc * 16 + tt;
        floatx4 c = (floatx4){0.f, 0.f, 0.f, 0.f};
#pragma unroll
        for (int kf = 0; kf < 2; ++kf) {
            short8 bv = *(const short8*)(V + (ttile * 16 + l15) * HDIM + kf * 32 + quad * 8);
            c = __builtin_amdgcn_mfma_f32_16x16x32_bf16(pa[kf], bv, c, 0, 0, 0);
        }
        int t = ttile * 16 + l15;
#pragma unroll
        for (int r = 0; r < 4; ++r) {
            int crow = wave * 16 + quad * 4 + r;
            int tout = crow * 16 + (t >> 6);
            int col = 512 + ((t & 63) << 3) + h;
            vp[(b * TP + 1 + tout) * (2 * DD) + col] = f2bf(c[r]);
        }
    }
}

// ---------------- output conv: A-only LDS dbuf, W2 streamed frag-major ----------------
// grid (T/128=8, 512/64=8, B=8) = 512 blocks. 4 waves as 2x2, wave tile 64x32.
__global__ __launch_bounds__(256) void k_out_conv(
    const unsigned short* __restrict__ vp, const unsigned short* __restrict__ w2k,
    const float* __restrict__ b2, float* __restrict__ out) {
    __shared__ short As[2][144 * 32];
    int wave = threadIdx.x >> 6, lane = threadIdx.x & 63;
    int l15 = lane & 15, quad = lane >> 4;
    int wm = wave >> 1, wn = wave & 1;
    int tb = blockIdx.x * 128;
    int cb = blockIdx.y * 64;
    int b = blockIdx.z;
    const short* A = (const short*)vp + b * TP * DD2;
    const short* WF = (const short*)w2k + lane * 8;
    int srow = lane >> 2;
    int scs = (((lane & 3) ^ (srow & 3)) << 3);
    int co0b = (cb >> 4) + wn * 2;

    floatx4 acc[4][2];
#pragma unroll
    for (int mi = 0; mi < 4; ++mi)
#pragma unroll
        for (int ni = 0; ni < 2; ++ni) acc[mi][ni] = (floatx4){0.f, 0.f, 0.f, 0.f};

    for (int j = wave; j < 9; j += 4)
        gl2lds16(A + (tb + j * 16 + srow) * DD2 + scs, &As[0][j * 512]);
    __syncthreads();

    for (int it = 0; it < 32; ++it) {
        if (it < 31) {
            for (int j = wave; j < 9; j += 4)
                gl2lds16(A + (tb + j * 16 + srow) * DD2 + (it + 1) * 32 + scs,
                         &As[(it + 1) & 1][j * 512]);
        }
        const short* Asb = As[it & 1];
        short8 bf[3][2];
#pragma unroll
        for (int k = 0; k < 3; ++k)
#pragma unroll
            for (int ni = 0; ni < 2; ++ni)
                bf[k][ni] = *(const short8*)(WF + ((size_t)((k * 32 + it) * 32 + co0b + ni) << 9));
#pragma unroll
        for (int k = 0; k < 3; ++k) {
            short8 af[4];
#pragma unroll
            for (int mi = 0; mi < 4; ++mi) {
                int arow = wm * 64 + mi * 16 + l15 + k;
                af[mi] = *(const short8*)&Asb[arow * 32 + ((quad ^ (arow & 3)) << 3)];
            }
#pragma unroll
            for (int mi = 0; mi < 4; ++mi)
#pragma unroll
                for (int ni = 0; ni < 2; ++ni)
                    acc[mi][ni] = __builtin_amdgcn_mfma_f32_16x16x32_bf16(af[mi], bf[k][ni], acc[mi][ni], 0, 0, 0);
        }
        __syncthreads();
    }

#pragma unroll
    for (int ni = 0; ni < 2; ++ni) {
        int co = cb + wn * 32 + ni * 16 + l15;
        float bv = b2[co];
#pragma unroll
        for (int mi = 0; mi < 4; ++mi) {
#pragma unroll
            for (int r = 0; r < 4; ++r) {
                int t = tb + wm * 64 + mi * 16 + quad * 4 + r;
                out[((size_t)b * TT + t) * DD + co] = fmaxf(acc[mi][ni][r] + bv, 0.f);
            }
        }
    }
}

extern "C" void kernel_launch(void* const* d_in, const int* in_sizes, int n_in,
                              void* d_out, int out_size, void* d_ws, size_t ws_size,
                              hipStream_t stream) {
    const float* x = (const float*)d_in[0];
    const float* w11 = (const float*)d_in[1];
    const float* b11 = (const float*)d_in[2];
    const float* w12 = (const float*)d_in[3];
    const float* b12 = (const float*)d_in[4];
    const float* w13 = (const float*)d_in[5];
    const float* b13 = (const float*)d_in[6];
    const float* w2 = (const float*)d_in[7];
    const float* b2 = (const float*)d_in[8];
    float* out = (float*)d_out;

    char* ws = (char*)d_ws;
    size_t off = 0;
    auto alloc = [&](size_t bytes) {
        void* p = ws + off;
        off += (bytes + 255) & ~(size_t)255;
        return p;
    };
    unsigned short* xp = (unsigned short*)alloc((size_t)BB * TP * DD * 2);
    unsigned short* wqkv = (unsigned short*)alloc((size_t)9 * DD * DD * 2);
    unsigned short* w2k = (unsigned short*)alloc((size_t)3 * DD * DD2 * 2);
    unsigned short* q = (unsigned short*)alloc((size_t)BB * HH * TT * HDIM * 2);
    unsigned short* qt = (unsigned short*)alloc((size_t)BB * HH * TT * HDIM * 2);
    unsigned short* kfrag = (unsigned short*)alloc((size_t)BB * HH * TT * HDIM * 2);
    unsigned short* kt = (unsigned short*)alloc((size_t)BB * HH * TT * HDIM * 2);
    unsigned short* v = (unsigned short*)alloc((size_t)BB * HH * TT * HDIM * 2);
    unsigned short* vtfrag = (unsigned short*)alloc((size_t)BB * HH * TT * HDIM * 2);
    float* gbuf = (float*)alloc((size_t)64 * HDIM * HDIM * 4);
    unsigned short* vp = (unsigned short*)alloc((size_t)BB * TP * 2 * DD * 2);
    (void)alloc(65536);  // guard: halo staging reads up to 14 rows past vp end

    k_convert_x<<<(BB * TP * DD + 255) / 256, 256, 0, stream>>>(x, xp);
    k_convert_wqkv<<<((9 << 18) + 255) / 256, 256, 0, stream>>>(w11, w12, w13, wqkv);
    k_convert_w2<<<((3 << 19) + 255) / 256, 256, 0, stream>>>(w2, w2k);
    k_zero_aux<<<(64 * HDIM * HDIM + 255) / 256, 256, 0, stream>>>(vp, gbuf);
    k_qkv_conv<<<dim3(TT / 128, DD / 128, BB * 3), 256, 0, stream>>>(xp, wqkv, b11, b12, b13,
                                                                     q, qt, kfrag, kt, v, vtfrag);
    k_time_attn<<<dim3(TT / 64, BB * HH), 256, 0, stream>>>(q, kfrag, vtfrag, vp);
    k_chan_gram<<<dim3(4, BB * HH), 256, 0, stream>>>(qt, kt, gbuf);
    k_chan_av<<<dim3(4, BB * HH), 256, 0, stream>>>(gbuf, v, vp);
    k_out_conv<<<dim3(TT / 128, DD / 64, BB), 256, 0, stream>>>(vp, w2k, b2, out);
}

// Round 9
// 246.337 us; speedup vs baseline: 1.4816x; 1.0717x over previous
//
#include <hip/hip_runtime.h>

#define BB 8
#define TT 1024
#define DD 512
#define DD2 1024
#define HH 8
#define HDIM 64
#define TP (TT + 2)

typedef short short8 __attribute__((ext_vector_type(8)));
typedef float floatx4 __attribute__((ext_vector_type(4)));

typedef const __attribute__((address_space(1))) unsigned int* gas_ptr;
typedef __attribute__((address_space(3))) unsigned int* las_ptr;

__device__ __forceinline__ unsigned short f2bf(float f) {
    union { float f; unsigned u; } v; v.f = f;
    unsigned r = v.u + 0x7fffu + ((v.u >> 16) & 1u);
    return (unsigned short)(r >> 16);
}

// async global->LDS, 16B per lane, LDS dst = wave-uniform base + lane*16
__device__ __forceinline__ void gl2lds16(const void* g, void* l) {
    __builtin_amdgcn_global_load_lds((gas_ptr)g, (las_ptr)l, 16, 0, 0);
}

// ---------------- fused prep kernel ----------------
// ranges: [0, NX) convert_x | [NX, NX+NW1) wqkv frag | [.., +NW2) w2 frag | [.., +NZ) zero
#define NXBLK 16416
#define NW1BLK 9216
#define NW2BLK 6144
#define NZBLK 1024
__global__ void k_prep(const float* __restrict__ x, const float* __restrict__ w0,
                       const float* __restrict__ w1, const float* __restrict__ w2,
                       const float* __restrict__ wo,
                       unsigned short* __restrict__ xp, unsigned short* __restrict__ wqkv,
                       unsigned short* __restrict__ w2k, unsigned short* __restrict__ vp,
                       float* __restrict__ gbuf) {
    int blk = blockIdx.x;
    if (blk < NXBLK) {
        int idx = blk * 256 + threadIdx.x;
        int c = idx % DD;
        int rt = idx / DD;
        int row = rt % TP;
        int b = rt / TP;
        float v = 0.f;
        if (row >= 1 && row <= TT) v = x[(b * TT + row - 1) * DD + c];
        xp[idx] = f2bf(v);
        return;
    }
    blk -= NXBLK;
    if (blk < NW1BLK) {
        // W(qkv) B-frag-major: [proj][k][ci0(16)][co0(32)][lane(64)][e(8)]
        int idx = blk * 256 + threadIdx.x;
        int e = idx & 7;
        int lane = (idx >> 3) & 63;
        int co0 = (idx >> 9) & 31;
        int ci0 = (idx >> 14) & 15;
        int rest = idx >> 18;
        int k = rest % 3, p = rest / 3;
        int co = co0 * 16 + (lane & 15);
        int ci = ci0 * 32 + (lane >> 4) * 8 + e;
        const float* w = (p == 0) ? w0 : ((p == 1) ? w1 : w2);
        wqkv[idx] = f2bf(w[(co * DD + ci) * 3 + k]);
        return;
    }
    blk -= NW1BLK;
    if (blk < NW2BLK) {
        // W2 B-frag-major: [k][ci0(32)][co0(32)][lane(64)][e(8)]
        int idx = blk * 256 + threadIdx.x;
        int e = idx & 7;
        int lane = (idx >> 3) & 63;
        int co0 = (idx >> 9) & 31;
        int ci0 = (idx >> 14) & 31;
        int k = idx >> 19;
        int co = co0 * 16 + (lane & 15);
        int ci = ci0 * 32 + (lane >> 4) * 8 + e;
        w2k[idx] = f2bf(wo[(co * DD2 + ci) * 3 + k]);
        return;
    }
    blk -= NW2BLK;
    {
        int idx = blk * 256 + threadIdx.x;
        if (idx < BB * 2 * 2 * DD) {
            int c = idx % (2 * DD);
            int t1 = idx / (2 * DD);
            int row = (t1 & 1) ? (TT + 1) : 0;
            int b = t1 >> 1;
            vp[(b * TP + row) * (2 * DD) + c] = 0;
        }
        if (idx < 64 * HDIM * HDIM) gbuf[idx] = 0.f;
    }
}

// ---------------- QKV conv: BK=64 A-dbuf (18 KB/buf), 3-bit XOR swizzle, W streamed ----
// grid (T/128=8, 512/128=4, B*3=24), 256 thr = 4 waves (2x2), wave tile 64x64.
// A stage: DMA (j,hf) covers 8 rows x 128B; lane l -> row hf*8+(l>>3), phys chunk l&7,
// source logical chunk (l&7)^(l>>3). Read: logical cl at phys cl^(arow&7) -> 0 conflicts.
__global__ __launch_bounds__(256) void k_qkv_conv(
    const unsigned short* __restrict__ xp, const unsigned short* __restrict__ wfrag,
    const float* __restrict__ b11, const float* __restrict__ b12, const float* __restrict__ b13,
    unsigned short* __restrict__ q, unsigned short* __restrict__ qt,
    unsigned short* __restrict__ kfrag, unsigned short* __restrict__ kt,
    unsigned short* __restrict__ v, unsigned short* __restrict__ vtfrag) {
    __shared__ short As[2][144 * 64];
    int wave = threadIdx.x >> 6, lane = threadIdx.x & 63;
    int l15 = lane & 15, quad = lane >> 4;
    int wm = wave >> 1, wn = wave & 1;
    int tb = blockIdx.x * 128;
    int cb = blockIdx.y * 128;
    int proj = blockIdx.z % 3, b = blockIdx.z / 3;
    const short* A = (const short*)xp + b * TP * DD;
    const short* WF = (const short*)wfrag + (size_t)proj * 786432 + lane * 8;
    int srow8 = lane >> 3;                            // 0..7 row within DMA
    int scl = ((lane & 7) ^ srow8) * 8;               // swizzled source chunk offset (shorts)
    int co0b = (cb >> 4) + wn * 4;

    floatx4 acc[4][4];
#pragma unroll
    for (int mi = 0; mi < 4; ++mi)
#pragma unroll
        for (int ni = 0; ni < 4; ++ni) acc[mi][ni] = (floatx4){0.f, 0.f, 0.f, 0.f};

    // stage(it) into As[it&1]: 18 DMAs distributed over 4 waves
    auto stage = [&](int it) {
        short* dst = As[it & 1];
        int cib = it * 64;
        for (int g = wave; g < 18; g += 4) {
            int j = g >> 1, hf = g & 1;
            int row = hf * 8 + srow8;
            gl2lds16(A + (tb + j * 16 + row) * DD + cib + scl, &dst[j * 1024 + hf * 512]);
        }
    };

    stage(0);
    __syncthreads();

    for (int it = 0; it < 8; ++it) {
        if (it < 7) stage(it + 1);
        const short* Asb = As[it & 1];
#pragma unroll
        for (int k = 0; k < 3; ++k) {
            short8 bf[2][4];
#pragma unroll
            for (int kfh = 0; kfh < 2; ++kfh)
#pragma unroll
                for (int ni = 0; ni < 4; ++ni)
                    bf[kfh][ni] = *(const short8*)(WF +
                        ((size_t)((k * 16 + it * 2 + kfh) * 32 + co0b + ni) << 9));
#pragma unroll
            for (int kfh = 0; kfh < 2; ++kfh) {
                short8 af[4];
#pragma unroll
                for (int mi = 0; mi < 4; ++mi) {
                    int arow = wm * 64 + mi * 16 + l15 + k;
                    int cl = kfh * 4 + quad;
                    af[mi] = *(const short8*)&Asb[arow * 64 + ((cl ^ (arow & 7)) << 3)];
                }
#pragma unroll
                for (int mi = 0; mi < 4; ++mi)
#pragma unroll
                    for (int ni = 0; ni < 4; ++ni)
                        acc[mi][ni] = __builtin_amdgcn_mfma_f32_16x16x32_bf16(af[mi], bf[kfh][ni], acc[mi][ni], 0, 0, 0);
            }
        }
        __syncthreads();
    }

    const float* bias = (proj == 0) ? b11 : ((proj == 1) ? b12 : b13);
#pragma unroll
    for (int ni = 0; ni < 4; ++ni) {
        int co = cb + wn * 64 + ni * 16 + l15;
        float bv = bias[co];
        int h = co >> 6, hd = co & 63;
        int bh = b * HH + h;
#pragma unroll
        for (int mi = 0; mi < 4; ++mi) {
            int tbase = tb + wm * 64 + mi * 16 + quad * 4;
            unsigned short bb[4];
            ushort4 pk;
#pragma unroll
            for (int r = 0; r < 4; ++r) {
                float val = fmaxf(acc[mi][ni][r] + bv, 0.f);
                bb[r] = f2bf(val);
                ((unsigned short*)&pk)[r] = bb[r];
            }
            if (proj == 0) {
#pragma unroll
                for (int r = 0; r < 4; ++r)
                    q[((size_t)bh * TT + tbase + r) * HDIM + hd] = bb[r];
                *(ushort4*)&qt[((size_t)bh * HDIM + hd) * TT + tbase] = pk;
            } else if (proj == 1) {
                *(ushort4*)&kt[((size_t)bh * HDIM + hd) * TT + tbase] = pk;
                // K-frag layout: [bh][sblk][jr][kf][quad_a*16+l15a][8]
                int sblk = tbase >> 6;
                int jr = (quad & 1) + 2 * (mi >> 1);
                int l15a_base = 4 * (quad >> 1) + 8 * (mi & 1);  // + r
                int kf = hd >> 5, quad_a = (hd >> 3) & 3, elem = hd & 7;
                size_t base = ((((size_t)bh * 16 + sblk) * 4 + jr) * 2 + kf) * 512 +
                              quad_a * 128 + elem;
#pragma unroll
                for (int r = 0; r < 4; ++r)
                    kfrag[base + (l15a_base + r) * 8] = bb[r];
            } else {
#pragma unroll
                for (int r = 0; r < 4; ++r)
                    v[((size_t)bh * TT + tbase + r) * HDIM + hd] = bb[r];
                // Vt-frag layout: [bh][sblk][df][kf][quad_a*16+l15a][8]
                int sblk = tbase >> 6;
                int df = hd >> 4, l15a = hd & 15;
                int kf = mi >> 1;
                int quad_a = 2 * (mi & 1) + (quad >> 1);
                int elem = (quad & 1) * 4;
                size_t base = ((((size_t)bh * 16 + sblk) * 4 + df) * 2 + kf) * 512 +
                              (quad_a * 16 + l15a) * 8 + elem;
                *(ushort4*)&vtfrag[base] = pk;
            }
        }
    }
}

// ---------------- time attention: all-register flash, lane-linear frag loads ----------
// grid (T/64=16, B*H=64), block 256; each wave owns 16 Q rows (q = l15).
__global__ __launch_bounds__(256) void k_time_attn(
    const unsigned short* __restrict__ q, const unsigned short* __restrict__ kfrag,
    const unsigned short* __restrict__ vtfrag, unsigned short* __restrict__ vp) {
    int wave = threadIdx.x >> 6, lane = threadIdx.x & 63;
    int l15 = lane & 15, quad = lane >> 4;
    int bh = blockIdx.y;
    int b = bh >> 3, h = bh & 7;
    int qr = blockIdx.x * 64 + wave * 16;
    const short* Q = (const short*)q + (size_t)bh * TT * HDIM;
    const short* KF = (const short*)kfrag + (size_t)bh * 16 * 8 * 512 + lane * 8;
    const short* VF = (const short*)vtfrag + (size_t)bh * 16 * 8 * 512 + lane * 8;

    short8 bq[2];
#pragma unroll
    for (int kf = 0; kf < 2; ++kf)
        bq[kf] = *(const short8*)(Q + (qr + l15) * HDIM + kf * 32 + quad * 8);

    floatx4 o[4];  // O^T accum: d = df*16 + quad*4 + r, q = l15
#pragma unroll
    for (int df = 0; df < 4; ++df) o[df] = (floatx4){0.f, 0.f, 0.f, 0.f};
    float lacc = 0.f;

    for (int sblk = 0; sblk < 16; ++sblk) {
        const short* kp = KF + sblk * 8 * 512;
        const short* vv = VF + sblk * 8 * 512;
        floatx4 c[4];
#pragma unroll
        for (int jr = 0; jr < 4; ++jr) c[jr] = (floatx4){0.f, 0.f, 0.f, 0.f};
#pragma unroll
        for (int jr = 0; jr < 4; ++jr) {
#pragma unroll
            for (int kf = 0; kf < 2; ++kf) {
                short8 ak = *(const short8*)(kp + (jr * 2 + kf) * 512);
                c[jr] = __builtin_amdgcn_mfma_f32_16x16x32_bf16(ak, bq[kf], c[jr], 0, 0, 0);
            }
        }
        short8 pb[2];
#pragma unroll
        for (int kf = 0; kf < 2; ++kf) {
            union { short8 s; unsigned u[4]; } pk;
#pragma unroll
            for (int half = 0; half < 2; ++half) {
                floatx4 cc = c[2 * kf + half];
                float p0 = __expf(cc[0] * 0.125f);
                float p1 = __expf(cc[1] * 0.125f);
                float p2 = __expf(cc[2] * 0.125f);
                float p3 = __expf(cc[3] * 0.125f);
                lacc += (p0 + p1) + (p2 + p3);
                pk.u[half * 2] =
                    __builtin_amdgcn_perm(__float_as_uint(p1), __float_as_uint(p0), 0x07060302u);
                pk.u[half * 2 + 1] =
                    __builtin_amdgcn_perm(__float_as_uint(p3), __float_as_uint(p2), 0x07060302u);
            }
            pb[kf] = pk.s;
        }
#pragma unroll
        for (int df = 0; df < 4; ++df) {
#pragma unroll
            for (int kf = 0; kf < 2; ++kf) {
                short8 av = *(const short8*)(vv + (df * 2 + kf) * 512);
                o[df] = __builtin_amdgcn_mfma_f32_16x16x32_bf16(av, pb[kf], o[df], 0, 0, 0);
            }
        }
    }

    lacc += __shfl_xor(lacc, 16);
    lacc += __shfl_xor(lacc, 32);
    float linv = 1.f / lacc;

    unsigned short* vrow = vp + (size_t)(b * TP + 1 + qr + l15) * (2 * DD) + h * 64;
#pragma unroll
    for (int df = 0; df < 4; ++df) {
        ushort4 pk;
#pragma unroll
        for (int r = 0; r < 4; ++r) ((unsigned short*)&pk)[r] = f2bf(o[df][r] * linv);
        *(ushort4*)&vrow[df * 16 + quad * 4] = pk;
    }
}

// ---------------- channel attention: Gram partials (4-way T split) ----------------
__global__ __launch_bounds__(256) void k_chan_gram(
    const unsigned short* __restrict__ qt, const unsigned short* __restrict__ kt,
    float* __restrict__ gbuf) {
    int wave = threadIdx.x >> 6, lane = threadIdx.x & 63;
    int l15 = lane & 15, quad = lane >> 4;
    int tc = blockIdx.x, bh = blockIdx.y;
    const short* Qt = (const short*)qt + (size_t)bh * HDIM * TT;
    const short* Kt = (const short*)kt + (size_t)bh * HDIM * TT;

    floatx4 g[4];
#pragma unroll
    for (int nt = 0; nt < 4; ++nt) g[nt] = (floatx4){0.f, 0.f, 0.f, 0.f};

    int t0b = tc * 256;
    for (int t0 = 0; t0 < 256; t0 += 32) {
        short8 aq = *(const short8*)(Qt + (wave * 16 + l15) * TT + t0b + t0 + quad * 8);
#pragma unroll
        for (int nt = 0; nt < 4; ++nt) {
            short8 bk = *(const short8*)(Kt + (nt * 16 + l15) * TT + t0b + t0 + quad * 8);
            g[nt] = __builtin_amdgcn_mfma_f32_16x16x32_bf16(aq, bk, g[nt], 0, 0, 0);
        }
    }
    float* gb = gbuf + bh * HDIM * HDIM;
#pragma unroll
    for (int nt = 0; nt < 4; ++nt) {
#pragma unroll
        for (int r = 0; r < 4; ++r) {
            int row = wave * 16 + quad * 4 + r;
            atomicAdd(&gb[row * HDIM + nt * 16 + l15], g[nt][r]);
        }
    }
}

// ---------------- channel attention: softmax + A.V (4-way T split) ----------------
__global__ __launch_bounds__(256) void k_chan_av(
    const float* __restrict__ gbuf, const unsigned short* __restrict__ v,
    unsigned short* __restrict__ vp) {
    __shared__ short lds_a[64 * 64];
    int wave = threadIdx.x >> 6, lane = threadIdx.x & 63;
    int l15 = lane & 15, quad = lane >> 4;
    int tc = blockIdx.x, bh = blockIdx.y;
    int b = bh >> 3, h = bh & 7;
    const float sc = 0.03125f;  // 1/sqrt(1024)

    if (threadIdx.x < 64) {
        const float* gb = gbuf + bh * HDIM * HDIM + threadIdx.x * HDIM;
        float mx = -3.0e38f;
        for (int j = 0; j < 64; ++j) mx = fmaxf(mx, gb[j] * sc);
        float sum = 0.f;
        for (int j = 0; j < 64; ++j) sum += __expf(gb[j] * sc - mx);
        float inv = 1.f / sum;
        for (int j = 0; j < 64; ++j)
            lds_a[threadIdx.x * 64 + j] = (short)f2bf(__expf(gb[j] * sc - mx) * inv);
    }
    __syncthreads();

    const short* V = (const short*)v + (size_t)bh * TT * HDIM;
    short8 pa[2];
#pragma unroll
    for (int kf = 0; kf < 2; ++kf)
        pa[kf] = *(const short8*)&lds_a[(wave * 16 + l15) * 64 + kf * 32 + quad * 8];

    for (int tt = 0; tt < 16; ++tt) {
        int ttile = tc * 16 + tt;
        floatx4 c = (floatx4){0.f, 0.f, 0.f, 0.f};
#pragma unroll
        for (int kf = 0; kf < 2; ++kf) {
            short8 bv = *(const short8*)(V + (ttile * 16 + l15) * HDIM + kf * 32 + quad * 8);
            c = __builtin_amdgcn_mfma_f32_16x16x32_bf16(pa[kf], bv, c, 0, 0, 0);
        }
        int t = ttile * 16 + l15;
#pragma unroll
        for (int r = 0; r < 4; ++r) {
            int crow = wave * 16 + quad * 4 + r;
            int tout = crow * 16 + (t >> 6);
            int col = 512 + ((t & 63) << 3) + h;
            vp[(b * TP + 1 + tout) * (2 * DD) + col] = f2bf(c[r]);
        }
    }
}

// ---------------- output conv: BK=64 A-dbuf, 3-bit XOR swizzle, W2 streamed ----------
// grid (T/128=8, 512/64=8, B=8) = 512 blocks. 4 waves as 2x2, wave tile 64x32.
__global__ __launch_bounds__(256) void k_out_conv(
    const unsigned short* __restrict__ vp, const unsigned short* __restrict__ w2k,
    const float* __restrict__ b2, float* __restrict__ out) {
    __shared__ short As[2][144 * 64];
    int wave = threadIdx.x >> 6, lane = threadIdx.x & 63;
    int l15 = lane & 15, quad = lane >> 4;
    int wm = wave >> 1, wn = wave & 1;
    int tb = blockIdx.x * 128;
    int cb = blockIdx.y * 64;
    int b = blockIdx.z;
    const short* A = (const short*)vp + b * TP * DD2;
    const short* WF = (const short*)w2k + lane * 8;
    int srow8 = lane >> 3;
    int scl = ((lane & 7) ^ srow8) * 8;
    int co0b = (cb >> 4) + wn * 2;

    floatx4 acc[4][2];
#pragma unroll
    for (int mi = 0; mi < 4; ++mi)
#pragma unroll
        for (int ni = 0; ni < 2; ++ni) acc[mi][ni] = (floatx4){0.f, 0.f, 0.f, 0.f};

    auto stage = [&](int it) {
        short* dst = As[it & 1];
        int cib = it * 64;
        for (int g = wave; g < 18; g += 4) {
            int j = g >> 1, hf = g & 1;
            int row = hf * 8 + srow8;
            gl2lds16(A + (tb + j * 16 + row) * DD2 + cib + scl, &dst[j * 1024 + hf * 512]);
        }
    };

    stage(0);
    __syncthreads();

    for (int it = 0; it < 16; ++it) {
        if (it < 15) stage(it + 1);
        const short* Asb = As[it & 1];
#pragma unroll
        for (int k = 0; k < 3; ++k) {
            short8 bf[2][2];
#pragma unroll
            for (int kfh = 0; kfh < 2; ++kfh)
#pragma unroll
                for (int ni = 0; ni < 2; ++ni)
                    bf[kfh][ni] = *(const short8*)(WF +
                        ((size_t)((k * 32 + it * 2 + kfh) * 32 + co0b + ni) << 9));
#pragma unroll
            for (int kfh = 0; kfh < 2; ++kfh) {
                short8 af[4];
#pragma unroll
                for (int mi = 0; mi < 4; ++mi) {
                    int arow = wm * 64 + mi * 16 + l15 + k;
                    int cl = kfh * 4 + quad;
                    af[mi] = *(const short8*)&Asb[arow * 64 + ((cl ^ (arow & 7)) << 3)];
                }
#pragma unroll
                for (int mi = 0; mi < 4; ++mi)
#pragma unroll
                    for (int ni = 0; ni < 2; ++ni)
                        acc[mi][ni] = __builtin_amdgcn_mfma_f32_16x16x32_bf16(af[mi], bf[kfh][ni], acc[mi][ni], 0, 0, 0);
            }
        }
        __syncthreads();
    }

#pragma unroll
    for (int ni = 0; ni < 2; ++ni) {
        int co = cb + wn * 32 + ni * 16 + l15;
        float bv = b2[co];
#pragma unroll
        for (int mi = 0; mi < 4; ++mi) {
#pragma unroll
            for (int r = 0; r < 4; ++r) {
                int t = tb + wm * 64 + mi * 16 + quad * 4 + r;
                out[((size_t)b * TT + t) * DD + co] = fmaxf(acc[mi][ni][r] + bv, 0.f);
            }
        }
    }
}

extern "C" void kernel_launch(void* const* d_in, const int* in_sizes, int n_in,
                              void* d_out, int out_size, void* d_ws, size_t ws_size,
                              hipStream_t stream) {
    const float* x = (const float*)d_in[0];
    const float* w11 = (const float*)d_in[1];
    const float* b11 = (const float*)d_in[2];
    const float* w12 = (const float*)d_in[3];
    const float* b12 = (const float*)d_in[4];
    const float* w13 = (const float*)d_in[5];
    const float* b13 = (const float*)d_in[6];
    const float* w2 = (const float*)d_in[7];
    const float* b2 = (const float*)d_in[8];
    float* out = (float*)d_out;

    char* ws = (char*)d_ws;
    size_t off = 0;
    auto alloc = [&](size_t bytes) {
        void* p = ws + off;
        off += (bytes + 255) & ~(size_t)255;
        return p;
    };
    unsigned short* xp = (unsigned short*)alloc((size_t)BB * TP * DD * 2);
    unsigned short* wqkv = (unsigned short*)alloc((size_t)9 * DD * DD * 2);
    unsigned short* w2k = (unsigned short*)alloc((size_t)3 * DD * DD2 * 2);
    unsigned short* q = (unsigned short*)alloc((size_t)BB * HH * TT * HDIM * 2);
    unsigned short* qt = (unsigned short*)alloc((size_t)BB * HH * TT * HDIM * 2);
    unsigned short* kfrag = (unsigned short*)alloc((size_t)BB * HH * TT * HDIM * 2);
    unsigned short* kt = (unsigned short*)alloc((size_t)BB * HH * TT * HDIM * 2);
    unsigned short* v = (unsigned short*)alloc((size_t)BB * HH * TT * HDIM * 2);
    unsigned short* vtfrag = (unsigned short*)alloc((size_t)BB * HH * TT * HDIM * 2);
    float* gbuf = (float*)alloc((size_t)64 * HDIM * HDIM * 4);
    unsigned short* vp = (unsigned short*)alloc((size_t)BB * TP * 2 * DD * 2);
    (void)alloc(65536);  // guard: halo staging reads up to 14 rows past vp end

    k_prep<<<NXBLK + NW1BLK + NW2BLK + NZBLK, 256, 0, stream>>>(x, w11, w12, w13, w2,
                                                                xp, wqkv, w2k, vp, gbuf);
    k_qkv_conv<<<dim3(TT / 128, DD / 128, BB * 3), 256, 0, stream>>>(xp, wqkv, b11, b12, b13,
                                                                     q, qt, kfrag, kt, v, vtfrag);
    k_time_attn<<<dim3(TT / 64, BB * HH), 256, 0, stream>>>(q, kfrag, vtfrag, vp);
    k_chan_gram<<<dim3(4, BB * HH), 256, 0, stream>>>(qt, kt, gbuf);
    k_chan_av<<<dim3(4, BB * HH), 256, 0, stream>>>(gbuf, v, vp);
    k_out_conv<<<dim3(TT / 128, DD / 64, BB), 256, 0, stream>>>(vp, w2k, b2, out);
}

// Round 10
// 240.143 us; speedup vs baseline: 1.5198x; 1.0258x over previous
//
#include <hip/hip_runtime.h>

#define BB 8
#define TT 1024
#define DD 512
#define DD2 1024
#define HH 8
#define HDIM 64
#define TP (TT + 2)

typedef short short8 __attribute__((ext_vector_type(8)));
typedef float floatx4 __attribute__((ext_vector_type(4)));

typedef const __attribute__((address_space(1))) unsigned int* gas_ptr;
typedef __attribute__((address_space(3))) unsigned int* las_ptr;

__device__ __forceinline__ unsigned short f2bf(float f) {
    union { float f; unsigned u; } v; v.f = f;
    unsigned r = v.u + 0x7fffu + ((v.u >> 16) & 1u);
    return (unsigned short)(r >> 16);
}

// async global->LDS, 16B per lane, LDS dst = wave-uniform base + lane*16
__device__ __forceinline__ void gl2lds16(const void* g, void* l) {
    __builtin_amdgcn_global_load_lds((gas_ptr)g, (las_ptr)l, 16, 0, 0);
}

// ---------------- fused prep kernel ----------------
#define NXBLK 16416
#define NW1BLK 9216
#define NW2BLK 6144
#define NZBLK 1024
__global__ void k_prep(const float* __restrict__ x, const float* __restrict__ w0,
                       const float* __restrict__ w1, const float* __restrict__ w2,
                       const float* __restrict__ wo,
                       unsigned short* __restrict__ xp, unsigned short* __restrict__ wqkv,
                       unsigned short* __restrict__ w2k, unsigned short* __restrict__ vp,
                       float* __restrict__ gbuf) {
    int blk = blockIdx.x;
    if (blk < NXBLK) {
        int idx = blk * 256 + threadIdx.x;
        int c = idx % DD;
        int rt = idx / DD;
        int row = rt % TP;
        int b = rt / TP;
        float v = 0.f;
        if (row >= 1 && row <= TT) v = x[(b * TT + row - 1) * DD + c];
        xp[idx] = f2bf(v);
        return;
    }
    blk -= NXBLK;
    if (blk < NW1BLK) {
        // W(qkv) B-frag-major: [proj][k][ci0(16)][co0(32)][lane(64)][e(8)]
        int idx = blk * 256 + threadIdx.x;
        int e = idx & 7;
        int lane = (idx >> 3) & 63;
        int co0 = (idx >> 9) & 31;
        int ci0 = (idx >> 14) & 15;
        int rest = idx >> 18;
        int k = rest % 3, p = rest / 3;
        int co = co0 * 16 + (lane & 15);
        int ci = ci0 * 32 + (lane >> 4) * 8 + e;
        const float* w = (p == 0) ? w0 : ((p == 1) ? w1 : w2);
        wqkv[idx] = f2bf(w[(co * DD + ci) * 3 + k]);
        return;
    }
    blk -= NW1BLK;
    if (blk < NW2BLK) {
        // W2 B-frag-major: [k][ci0(32)][co0(32)][lane(64)][e(8)]
        int idx = blk * 256 + threadIdx.x;
        int e = idx & 7;
        int lane = (idx >> 3) & 63;
        int co0 = (idx >> 9) & 31;
        int ci0 = (idx >> 14) & 31;
        int k = idx >> 19;
        int co = co0 * 16 + (lane & 15);
        int ci = ci0 * 32 + (lane >> 4) * 8 + e;
        w2k[idx] = f2bf(wo[(co * DD2 + ci) * 3 + k]);
        return;
    }
    blk -= NW2BLK;
    {
        int idx = blk * 256 + threadIdx.x;
        if (idx < BB * 2 * 2 * DD) {
            int c = idx % (2 * DD);
            int t1 = idx / (2 * DD);
            int row = (t1 & 1) ? (TT + 1) : 0;
            int b = t1 >> 1;
            vp[(b * TP + row) * (2 * DD) + c] = 0;
        }
        if (idx < 64 * HDIM * HDIM) gbuf[idx] = 0.f;
    }
}

// ---------------- QKV conv: 64x128 block tile, BK=32 dbuf (5 KB/buf), W streamed ------
// grid (T/64=16, 512/128=4, B*3=24) = 1536 blocks (~6/CU). 4 waves split N: wave w
// owns co [cb+w*32, +32), wave tile 64x32 (acc 4x2). Full XOR swizzle: staging lane l
// sources logical chunk (l&3)^((l>>3)&3); read phys = quad ^ ((arow>>1)&3) -> 2-way, free.
__global__ __launch_bounds__(256) void k_qkv_conv(
    const unsigned short* __restrict__ xp, const unsigned short* __restrict__ wfrag,
    const float* __restrict__ b11, const float* __restrict__ b12, const float* __restrict__ b13,
    unsigned short* __restrict__ q, unsigned short* __restrict__ qt,
    unsigned short* __restrict__ kfrag, unsigned short* __restrict__ kt,
    unsigned short* __restrict__ v, unsigned short* __restrict__ vtfrag) {
    __shared__ short As[2][80 * 32];
    int wave = threadIdx.x >> 6, lane = threadIdx.x & 63;
    int l15 = lane & 15, quad = lane >> 4;
    int tb = blockIdx.x * 64;
    int cb = blockIdx.y * 128;
    int proj = blockIdx.z % 3, b = blockIdx.z / 3;
    const short* A = (const short*)xp + b * TP * DD;
    const short* WF = (const short*)wfrag + (size_t)proj * 786432 + lane * 8;
    int srow = lane >> 2;                                  // staging row 0..15 within group
    int scs = (((lane & 3) ^ ((lane >> 3) & 3)) << 3);     // swizzled source chunk (shorts)
    int co0b = (cb >> 4) + wave * 2;

    floatx4 acc[4][2];
#pragma unroll
    for (int mi = 0; mi < 4; ++mi)
#pragma unroll
        for (int ni = 0; ni < 2; ++ni) acc[mi][ni] = (floatx4){0.f, 0.f, 0.f, 0.f};

    // stage(it): 5 row-groups of 16 rows x 64 B (halo rows tb..tb+79; consumed <= tb+65)
    auto stage = [&](int it) {
        short* dst = As[it & 1];
        int cib = it * 32;
        for (int j = wave; j < 5; j += 4)
            gl2lds16(A + (tb + j * 16 + srow) * DD + cib + scs, &dst[j * 512]);
    };

    stage(0);
    __syncthreads();

    for (int it = 0; it < 16; ++it) {
        if (it < 15) stage(it + 1);
        const short* Asb = As[it & 1];
        short8 bf[3][2];
#pragma unroll
        for (int k = 0; k < 3; ++k)
#pragma unroll
            for (int ni = 0; ni < 2; ++ni)
                bf[k][ni] = *(const short8*)(WF + ((size_t)((k * 16 + it) * 32 + co0b + ni) << 9));
#pragma unroll
        for (int k = 0; k < 3; ++k) {
            short8 af[4];
#pragma unroll
            for (int mi = 0; mi < 4; ++mi) {
                int arow = mi * 16 + l15 + k;
                af[mi] = *(const short8*)&Asb[arow * 32 + ((quad ^ ((arow >> 1) & 3)) << 3)];
            }
#pragma unroll
            for (int mi = 0; mi < 4; ++mi)
#pragma unroll
                for (int ni = 0; ni < 2; ++ni)
                    acc[mi][ni] = __builtin_amdgcn_mfma_f32_16x16x32_bf16(af[mi], bf[k][ni], acc[mi][ni], 0, 0, 0);
        }
        __syncthreads();
    }

    const float* bias = (proj == 0) ? b11 : ((proj == 1) ? b12 : b13);
#pragma unroll
    for (int ni = 0; ni < 2; ++ni) {
        int co = cb + wave * 32 + ni * 16 + l15;
        float bv = bias[co];
        int h = co >> 6, hd = co & 63;
        int bh = b * HH + h;
#pragma unroll
        for (int mi = 0; mi < 4; ++mi) {
            int tbase = tb + mi * 16 + quad * 4;
            unsigned short bb[4];
            ushort4 pk;
#pragma unroll
            for (int r = 0; r < 4; ++r) {
                float val = fmaxf(acc[mi][ni][r] + bv, 0.f);
                bb[r] = f2bf(val);
                ((unsigned short*)&pk)[r] = bb[r];
            }
            if (proj == 0) {
#pragma unroll
                for (int r = 0; r < 4; ++r)
                    q[((size_t)bh * TT + tbase + r) * HDIM + hd] = bb[r];
                *(ushort4*)&qt[((size_t)bh * HDIM + hd) * TT + tbase] = pk;
            } else if (proj == 1) {
                *(ushort4*)&kt[((size_t)bh * HDIM + hd) * TT + tbase] = pk;
                // K-frag layout: [bh][sblk][jr][kf][quad_a*16+l15a][8]
                int sblk = tbase >> 6;
                int jr = (quad & 1) + 2 * (mi >> 1);
                int l15a_base = 4 * (quad >> 1) + 8 * (mi & 1);  // + r
                int kf = hd >> 5, quad_a = (hd >> 3) & 3, elem = hd & 7;
                size_t base = ((((size_t)bh * 16 + sblk) * 4 + jr) * 2 + kf) * 512 +
                              quad_a * 128 + elem;
#pragma unroll
                for (int r = 0; r < 4; ++r)
                    kfrag[base + (l15a_base + r) * 8] = bb[r];
            } else {
#pragma unroll
                for (int r = 0; r < 4; ++r)
                    v[((size_t)bh * TT + tbase + r) * HDIM + hd] = bb[r];
                // Vt-frag layout: [bh][sblk][df][kf][quad_a*16+l15a][8]
                int sblk = tbase >> 6;
                int df = hd >> 4, l15a = hd & 15;
                int kf = mi >> 1;
                int quad_a = 2 * (mi & 1) + (quad >> 1);
                int elem = (quad & 1) * 4;
                size_t base = ((((size_t)bh * 16 + sblk) * 4 + df) * 2 + kf) * 512 +
                              (quad_a * 16 + l15a) * 8 + elem;
                *(ushort4*)&vtfrag[base] = pk;
            }
        }
    }
}

// ---------------- time attention: all-register flash, lane-linear frag loads ----------
// grid (T/64=16, B*H=64), block 256; each wave owns 16 Q rows (q = l15).
__global__ __launch_bounds__(256) void k_time_attn(
    const unsigned short* __restrict__ q, const unsigned short* __restrict__ kfrag,
    const unsigned short* __restrict__ vtfrag, unsigned short* __restrict__ vp) {
    int wave = threadIdx.x >> 6, lane = threadIdx.x & 63;
    int l15 = lane & 15, quad = lane >> 4;
    int bh = blockIdx.y;
    int b = bh >> 3, h = bh & 7;
    int qr = blockIdx.x * 64 + wave * 16;
    const short* Q = (const short*)q + (size_t)bh * TT * HDIM;
    const short* KF = (const short*)kfrag + (size_t)bh * 16 * 8 * 512 + lane * 8;
    const short* VF = (const short*)vtfrag + (size_t)bh * 16 * 8 * 512 + lane * 8;

    short8 bq[2];
#pragma unroll
    for (int kf = 0; kf < 2; ++kf)
        bq[kf] = *(const short8*)(Q + (qr + l15) * HDIM + kf * 32 + quad * 8);

    floatx4 o[4];  // O^T accum: d = df*16 + quad*4 + r, q = l15
#pragma unroll
    for (int df = 0; df < 4; ++df) o[df] = (floatx4){0.f, 0.f, 0.f, 0.f};
    float lacc = 0.f;

    for (int sblk = 0; sblk < 16; ++sblk) {
        const short* kp = KF + sblk * 8 * 512;
        const short* vv = VF + sblk * 8 * 512;
        floatx4 c[4];
#pragma unroll
        for (int jr = 0; jr < 4; ++jr) c[jr] = (floatx4){0.f, 0.f, 0.f, 0.f};
#pragma unroll
        for (int jr = 0; jr < 4; ++jr) {
#pragma unroll
            for (int kf = 0; kf < 2; ++kf) {
                short8 ak = *(const short8*)(kp + (jr * 2 + kf) * 512);
                c[jr] = __builtin_amdgcn_mfma_f32_16x16x32_bf16(ak, bq[kf], c[jr], 0, 0, 0);
            }
        }
        short8 pb[2];
#pragma unroll
        for (int kf = 0; kf < 2; ++kf) {
            union { short8 s; unsigned u[4]; } pk;
#pragma unroll
            for (int half = 0; half < 2; ++half) {
                floatx4 cc = c[2 * kf + half];
                float p0 = __expf(cc[0] * 0.125f);
                float p1 = __expf(cc[1] * 0.125f);
                float p2 = __expf(cc[2] * 0.125f);
                float p3 = __expf(cc[3] * 0.125f);
                lacc += (p0 + p1) + (p2 + p3);
                pk.u[half * 2] =
                    __builtin_amdgcn_perm(__float_as_uint(p1), __float_as_uint(p0), 0x07060302u);
                pk.u[half * 2 + 1] =
                    __builtin_amdgcn_perm(__float_as_uint(p3), __float_as_uint(p2), 0x07060302u);
            }
            pb[kf] = pk.s;
        }
#pragma unroll
        for (int df = 0; df < 4; ++df) {
#pragma unroll
            for (int kf = 0; kf < 2; ++kf) {
                short8 av = *(const short8*)(vv + (df * 2 + kf) * 512);
                o[df] = __builtin_amdgcn_mfma_f32_16x16x32_bf16(av, pb[kf], o[df], 0, 0, 0);
            }
        }
    }

    lacc += __shfl_xor(lacc, 16);
    lacc += __shfl_xor(lacc, 32);
    float linv = 1.f / lacc;

    unsigned short* vrow = vp + (size_t)(b * TP + 1 + qr + l15) * (2 * DD) + h * 64;
#pragma unroll
    for (int df = 0; df < 4; ++df) {
        ushort4 pk;
#pragma unroll
        for (int r = 0; r < 4; ++r) ((unsigned short*)&pk)[r] = f2bf(o[df][r] * linv);
        *(ushort4*)&vrow[df * 16 + quad * 4] = pk;
    }
}

// ---------------- channel attention: Gram partials (4-way T split) ----------------
__global__ __launch_bounds__(256) void k_chan_gram(
    const unsigned short* __restrict__ qt, const unsigned short* __restrict__ kt,
    float* __restrict__ gbuf) {
    int wave = threadIdx.x >> 6, lane = threadIdx.x & 63;
    int l15 = lane & 15, quad = lane >> 4;
    int tc = blockIdx.x, bh = blockIdx.y;
    const short* Qt = (const short*)qt + (size_t)bh * HDIM * TT;
    const short* Kt = (const short*)kt + (size_t)bh * HDIM * TT;

    floatx4 g[4];
#pragma unroll
    for (int nt = 0; nt < 4; ++nt) g[nt] = (floatx4){0.f, 0.f, 0.f, 0.f};

    int t0b = tc * 256;
    for (int t0 = 0; t0 < 256; t0 += 32) {
        short8 aq = *(const short8*)(Qt + (wave * 16 + l15) * TT + t0b + t0 + quad * 8);
#pragma unroll
        for (int nt = 0; nt < 4; ++nt) {
            short8 bk = *(const short8*)(Kt + (nt * 16 + l15) * TT + t0b + t0 + quad * 8);
            g[nt] = __builtin_amdgcn_mfma_f32_16x16x32_bf16(aq, bk, g[nt], 0, 0, 0);
        }
    }
    float* gb = gbuf + bh * HDIM * HDIM;
#pragma unroll
    for (int nt = 0; nt < 4; ++nt) {
#pragma unroll
        for (int r = 0; r < 4; ++r) {
            int row = wave * 16 + quad * 4 + r;
            atomicAdd(&gb[row * HDIM + nt * 16 + l15], g[nt][r]);
        }
    }
}

// ---------------- channel attention: softmax + A.V (4-way T split) ----------------
__global__ __launch_bounds__(256) void k_chan_av(
    const float* __restrict__ gbuf, const unsigned short* __restrict__ v,
    unsigned short* __restrict__ vp) {
    __shared__ short lds_a[64 * 64];
    int wave = threadIdx.x >> 6, lane = threadIdx.x & 63;
    int l15 = lane & 15, quad = lane >> 4;
    int tc = blockIdx.x, bh = blockIdx.y;
    int b = bh >> 3, h = bh & 7;
    const float sc = 0.03125f;  // 1/sqrt(1024)

    if (threadIdx.x < 64) {
        const float* gb = gbuf + bh * HDIM * HDIM + threadIdx.x * HDIM;
        float mx = -3.0e38f;
        for (int j = 0; j < 64; ++j) mx = fmaxf(mx, gb[j] * sc);
        float sum = 0.f;
        for (int j = 0; j < 64; ++j) sum += __expf(gb[j] * sc - mx);
        float inv = 1.f / sum;
        for (int j = 0; j < 64; ++j)
            lds_a[threadIdx.x * 64 + j] = (short)f2bf(__expf(gb[j] * sc - mx) * inv);
    }
    __syncthreads();

    const short* V = (const short*)v + (size_t)bh * TT * HDIM;
    short8 pa[2];
#pragma unroll
    for (int kf = 0; kf < 2; ++kf)
        pa[kf] = *(const short8*)&lds_a[(wave * 16 + l15) * 64 + kf * 32 + quad * 8];

    for (int tt = 0; tt < 16; ++tt) {
        int ttile = tc * 16 + tt;
        floatx4 c = (floatx4){0.f, 0.f, 0.f, 0.f};
#pragma unroll
        for (int kf = 0; kf < 2; ++kf) {
            short8 bv = *(const short8*)(V + (ttile * 16 + l15) * HDIM + kf * 32 + quad * 8);
            c = __builtin_amdgcn_mfma_f32_16x16x32_bf16(pa[kf], bv, c, 0, 0, 0);
        }
        int t = ttile * 16 + l15;
#pragma unroll
        for (int r = 0; r < 4; ++r) {
            int crow = wave * 16 + quad * 4 + r;
            int tout = crow * 16 + (t >> 6);
            int col = 512 + ((t & 63) << 3) + h;
            vp[(b * TP + 1 + tout) * (2 * DD) + col] = f2bf(c[r]);
        }
    }
}

// ---------------- output conv: BK=64 A-dbuf, 3-bit XOR swizzle, W2 streamed ----------
// grid (T/128=8, 512/64=8, B=8) = 512 blocks. 4 waves as 2x2, wave tile 64x32.
__global__ __launch_bounds__(256) void k_out_conv(
    const unsigned short* __restrict__ vp, const unsigned short* __restrict__ w2k,
    const float* __restrict__ b2, float* __restrict__ out) {
    __shared__ short As[2][144 * 64];
    int wave = threadIdx.x >> 6, lane = threadIdx.x & 63;
    int l15 = lane & 15, quad = lane >> 4;
    int wm = wave >> 1, wn = wave & 1;
    int tb = blockIdx.x * 128;
    int cb = blockIdx.y * 64;
    int b = blockIdx.z;
    const short* A = (const short*)vp + b * TP * DD2;
    const short* WF = (const short*)w2k + lane * 8;
    int srow8 = lane >> 3;
    int scl = ((lane & 7) ^ srow8) * 8;
    int co0b = (cb >> 4) + wn * 2;

    floatx4 acc[4][2];
#pragma unroll
    for (int mi = 0; mi < 4; ++mi)
#pragma unroll
        for (int ni = 0; ni < 2; ++ni) acc[mi][ni] = (floatx4){0.f, 0.f, 0.f, 0.f};

    auto stage = [&](int it) {
        short* dst = As[it & 1];
        int cib = it * 64;
        for (int g = wave; g < 18; g += 4) {
            int j = g >> 1, hf = g & 1;
            int row = hf * 8 + srow8;
            gl2lds16(A + (tb + j * 16 + row) * DD2 + cib + scl, &dst[j * 1024 + hf * 512]);
        }
    };

    stage(0);
    __syncthreads();

    for (int it = 0; it < 16; ++it) {
        if (it < 15) stage(it + 1);
        const short* Asb = As[it & 1];
#pragma unroll
        for (int k = 0; k < 3; ++k) {
            short8 bf[2][2];
#pragma unroll
            for (int kfh = 0; kfh < 2; ++kfh)
#pragma unroll
                for (int ni = 0; ni < 2; ++ni)
                    bf[kfh][ni] = *(const short8*)(WF +
                        ((size_t)((k * 32 + it * 2 + kfh) * 32 + co0b + ni) << 9));
#pragma unroll
            for (int kfh = 0; kfh < 2; ++kfh) {
                short8 af[4];
#pragma unroll
                for (int mi = 0; mi < 4; ++mi) {
                    int arow = wm * 64 + mi * 16 + l15 + k;
                    int cl = kfh * 4 + quad;
                    af[mi] = *(const short8*)&Asb[arow * 64 + ((cl ^ (arow & 7)) << 3)];
                }
#pragma unroll
                for (int mi = 0; mi < 4; ++mi)
#pragma unroll
                    for (int ni = 0; ni < 2; ++ni)
                        acc[mi][ni] = __builtin_amdgcn_mfma_f32_16x16x32_bf16(af[mi], bf[kfh][ni], acc[mi][ni], 0, 0, 0);
            }
        }
        __syncthreads();
    }

#pragma unroll
    for (int ni = 0; ni < 2; ++ni) {
        int co = cb + wn * 32 + ni * 16 + l15;
        float bv = b2[co];
#pragma unroll
        for (int mi = 0; mi < 4; ++mi) {
#pragma unroll
            for (int r = 0; r < 4; ++r) {
                int t = tb + wm * 64 + mi * 16 + quad * 4 + r;
                out[((size_t)b * TT + t) * DD + co] = fmaxf(acc[mi][ni][r] + bv, 0.f);
            }
        }
    }
}

extern "C" void kernel_launch(void* const* d_in, const int* in_sizes, int n_in,
                              void* d_out, int out_size, void* d_ws, size_t ws_size,
                              hipStream_t stream) {
    const float* x = (const float*)d_in[0];
    const float* w11 = (const float*)d_in[1];
    const float* b11 = (const float*)d_in[2];
    const float* w12 = (const float*)d_in[3];
    const float* b12 = (const float*)d_in[4];
    const float* w13 = (const float*)d_in[5];
    const float* b13 = (const float*)d_in[6];
    const float* w2 = (const float*)d_in[7];
    const float* b2 = (const float*)d_in[8];
    float* out = (float*)d_out;

    char* ws = (char*)d_ws;
    size_t off = 0;
    auto alloc = [&](size_t bytes) {
        void* p = ws + off;
        off += (bytes + 255) & ~(size_t)255;
        return p;
    };
    unsigned short* xp = (unsigned short*)alloc((size_t)BB * TP * DD * 2);
    unsigned short* wqkv = (unsigned short*)alloc((size_t)9 * DD * DD * 2);
    unsigned short* w2k = (unsigned short*)alloc((size_t)3 * DD * DD2 * 2);
    unsigned short* q = (unsigned short*)alloc((size_t)BB * HH * TT * HDIM * 2);
    unsigned short* qt = (unsigned short*)alloc((size_t)BB * HH * TT * HDIM * 2);
    unsigned short* kfrag = (unsigned short*)alloc((size_t)BB * HH * TT * HDIM * 2);
    unsigned short* kt = (unsigned short*)alloc((size_t)BB * HH * TT * HDIM * 2);
    unsigned short* v = (unsigned short*)alloc((size_t)BB * HH * TT * HDIM * 2);
    unsigned short* vtfrag = (unsigned short*)alloc((size_t)BB * HH * TT * HDIM * 2);
    float* gbuf = (float*)alloc((size_t)64 * HDIM * HDIM * 4);
    unsigned short* vp = (unsigned short*)alloc((size_t)BB * TP * 2 * DD * 2);
    (void)alloc(65536);  // guard: halo staging reads up to 14 rows past buffer ends

    k_prep<<<NXBLK + NW1BLK + NW2BLK + NZBLK, 256, 0, stream>>>(x, w11, w12, w13, w2,
                                                                xp, wqkv, w2k, vp, gbuf);
    k_qkv_conv<<<dim3(TT / 64, DD / 128, BB * 3), 256, 0, stream>>>(xp, wqkv, b11, b12, b13,
                                                                    q, qt, kfrag, kt, v, vtfrag);
    k_time_attn<<<dim3(TT / 64, BB * HH), 256, 0, stream>>>(q, kfrag, vtfrag, vp);
    k_chan_gram<<<dim3(4, BB * HH), 256, 0, stream>>>(qt, kt, gbuf);
    k_chan_av<<<dim3(4, BB * HH), 256, 0, stream>>>(gbuf, v, vp);
    k_out_conv<<<dim3(TT / 128, DD / 64, BB), 256, 0, stream>>>(vp, w2k, b2, out);
}